// Round 4
// baseline (6143.924 us; speedup 1.0000x reference)
//
#include <hip/hip_runtime.h>
#include <hip/hip_bf16.h>

// ---------------------------------------------------------------------------
// Conv-TasNet TCN, bf16-MFMA v3.
// GEMM: 128x128x64 tile (m97 structure), 4 waves (2x2), clean bf16 operands,
// global_load_lds_dwordx4 staging with both-sides XOR swizzle, 2-phase
// double-buffered pipeline with ONE barrier per K-step.
// GN folded as affine (GN1 into dw, GN2 into res/skip weights).
// Layout: activations [B][TP=4096][C] time-major.
// ---------------------------------------------------------------------------

#define T_  4000
#define TP_ 4096
#define B_  4

typedef __attribute__((ext_vector_type(8))) short  s8v;
typedef __attribute__((ext_vector_type(4))) float  f32x4;
typedef __attribute__((ext_vector_type(4))) unsigned short u16x4;

__device__ __forceinline__ float bf2f(unsigned short u) {
  unsigned int i = ((unsigned int)u) << 16;
  float f; __builtin_memcpy(&f, &i, 4); return f;
}
__device__ __forceinline__ unsigned short f2bf(float f) {
  unsigned int i; __builtin_memcpy(&i, &f, 4);
  unsigned int r = i + 0x7fffu + ((i >> 16) & 1u);
  return (unsigned short)(r >> 16);
}

__device__ __forceinline__ void g2lds16(const void* g, void* l) {
  __builtin_amdgcn_global_load_lds(
      (const __attribute__((address_space(1))) unsigned int*)g,
      (__attribute__((address_space(3))) unsigned int*)l, 16, 0, 0);
}

// ---------------- per-sample sum/sumsq over contiguous [C*T] ---------------
__global__ __launch_bounds__(256) void gn_stats(const float* __restrict__ X,
                                                float* __restrict__ statsOut, int n) {
  const int b = blockIdx.y;
  const float4* xp = (const float4*)(X + (size_t)b * n);
  const int n4 = n >> 2;
  float s1 = 0.f, s2 = 0.f;
  for (int idx = blockIdx.x * 256 + threadIdx.x; idx < n4; idx += gridDim.x * 256) {
    float4 v = xp[idx];
    s1 += v.x + v.y + v.z + v.w;
    s2 += v.x * v.x + v.y * v.y + v.z * v.z + v.w * v.w;
  }
#pragma unroll
  for (int off = 32; off > 0; off >>= 1) {
    s1 += __shfl_xor(s1, off);
    s2 += __shfl_xor(s2, off);
  }
  __shared__ float red[8];
  const int lane = threadIdx.x & 63, wv = threadIdx.x >> 6;
  if (lane == 0) { red[wv] = s1; red[4 + wv] = s2; }
  __syncthreads();
  if (threadIdx.x == 0) {
    atomicAdd(&statsOut[b * 2 + 0], red[0] + red[1] + red[2] + red[3]);
    atomicAdd(&statsOut[b * 2 + 1], red[4] + red[5] + red[6] + red[7]);
  }
}

// ---------------- weight prep ----------------------------------------------
__global__ __launch_bounds__(256) void cvt_bf(const float* __restrict__ s,
                                              unsigned short* __restrict__ d, int n) {
  for (int i = blockIdx.x * 256 + threadIdx.x; i < n; i += gridDim.x * 256)
    d[i] = f2bf(s[i]);
}

// GN2 fold: Wg[i][m][h] = bf16(w[m,h]*g2[i,h]); u=sum(w*g2); v=sum(w*b2)
__global__ __launch_bounds__(256) void fold_rs(
    const float* __restrict__ rw, const float* __restrict__ sw,
    const float* __restrict__ g2a, const float* __restrict__ b2a,
    unsigned short* __restrict__ Wg, float* __restrict__ Ucb,
    float* __restrict__ Vcb) {
  const int row = blockIdx.x;                 // i*256 + m
  const int i = row >> 8, m = row & 255;
  const float* src = (m < 128) ? rw + ((size_t)i * 128 + m) * 512
                               : sw + ((size_t)i * 128 + (m - 128)) * 512;
  const float* g = g2a + (size_t)i * 512;
  const float* bb = b2a + (size_t)i * 512;
  unsigned short* dst = Wg + (size_t)row * 512;
  float u = 0.f, v = 0.f;
  for (int h = threadIdx.x; h < 512; h += 256) {
    float wgt = src[h] * g[h];
    dst[h] = f2bf(wgt);
    u += wgt; v += src[h] * bb[h];
  }
  __shared__ float red[512];
  red[threadIdx.x] = u; red[256 + threadIdx.x] = v;
  __syncthreads();
  for (int off = 128; off > 0; off >>= 1) {
    if (threadIdx.x < off) {
      red[threadIdx.x] += red[threadIdx.x + off];
      red[256 + threadIdx.x] += red[256 + threadIdx.x + off];
    }
    __syncthreads();
  }
  if (threadIdx.x == 0) { Ucb[row] = red[0]; Vcb[row] = red[256]; }
}

// prelu + bf16 convert (heads input prep)
__global__ __launch_bounds__(256) void prelu_cvt(const float* __restrict__ S,
                                                 unsigned short* __restrict__ D,
                                                 const float* __restrict__ ap, int n) {
  const float a = ap[0];
  for (int i = blockIdx.x * 256 + threadIdx.x; i < n; i += gridDim.x * 256) {
    float v = S[i];
    v = v >= 0.f ? v : a * v;
    D[i] = f2bf(v);
  }
}

// ---------------- input transpose + GN affine + bf16 -----------------------
__global__ __launch_bounds__(256) void tin(const float* __restrict__ X,
                                           unsigned short* __restrict__ Xt,
                                           const float* __restrict__ g,
                                           const float* __restrict__ bt,
                                           const float* __restrict__ sIn, float invN) {
  const int b = blockIdx.z, c0 = blockIdx.y * 64, t0 = blockIdx.x * 64;
  __shared__ float tile[64][65];
  const int tid = threadIdx.x;
  const float mean = sIn[b * 2] * invN;
  const float rs = rsqrtf(sIn[b * 2 + 1] * invN - mean * mean + 1e-8f);
  {
    const int cl = tid >> 2, tq = (tid & 3) * 16;
    const float* Xr = X + ((size_t)b * 256 + c0 + cl) * T_;
#pragma unroll
    for (int j = 0; j < 4; ++j) {
      int tt = t0 + tq + j * 4;
      float4 v;
      if (tt + 3 < T_) v = *(const float4*)(Xr + tt);
      else {
        v.x = (tt + 0 < T_) ? Xr[tt + 0] : 0.f;
        v.y = (tt + 1 < T_) ? Xr[tt + 1] : 0.f;
        v.z = (tt + 2 < T_) ? Xr[tt + 2] : 0.f;
        v.w = (tt + 3 < T_) ? Xr[tt + 3] : 0.f;
      }
      tile[cl][tq + j * 4 + 0] = v.x; tile[cl][tq + j * 4 + 1] = v.y;
      tile[cl][tq + j * 4 + 2] = v.z; tile[cl][tq + j * 4 + 3] = v.w;
    }
  }
  __syncthreads();
  {
    const int tl = tid >> 2, cq = (tid & 3) * 16;
    const int t = t0 + tl;
    if (t < T_) {
      unsigned short* dst = Xt + ((size_t)b * TP_ + t) * 256 + c0 + cq;
      s8v u0, u1;
#pragma unroll
      for (int j = 0; j < 16; ++j) {
        int c = c0 + cq + j;
        float sc = rs * g[c];
        float oc = bt[c] - mean * sc;
        unsigned short uu = f2bf(tile[cq + j][tl] * sc + oc);
        if (j < 8) u0[j] = (short)uu; else u1[j - 8] = (short)uu;
      }
      *(s8v*)dst = u0;
      *(s8v*)(dst + 8) = u1;
    }
  }
}

// ---------------- feature_r: OUTS [t][128] fp32 -> feat [128][t] fp32 ------
__global__ __launch_bounds__(256) void tfeat(const float* __restrict__ O,
                                             float* __restrict__ F) {
  const int b = blockIdx.z, c0 = blockIdx.y * 64, t0 = blockIdx.x * 64;
  __shared__ float tile[64][65];
  const int tid = threadIdx.x;
  {
    const int tr = tid >> 2, cq = (tid & 3) * 16;
    const int t = t0 + tr;
#pragma unroll
    for (int j = 0; j < 4; ++j) {
      float4 v = make_float4(0.f, 0.f, 0.f, 0.f);
      if (t < T_) v = *(const float4*)(O + ((size_t)b * TP_ + t) * 128 + c0 + cq + j * 4);
      tile[tr][cq + j * 4 + 0] = v.x; tile[tr][cq + j * 4 + 1] = v.y;
      tile[tr][cq + j * 4 + 2] = v.z; tile[tr][cq + j * 4 + 3] = v.w;
    }
  }
  __syncthreads();
  {
    const int cl = tid >> 2, tq = (tid & 3) * 16;
    float* Fr = F + ((size_t)b * 128 + c0 + cl) * T_;
#pragma unroll
    for (int j = 0; j < 4; ++j) {
      int tt = t0 + tq + j * 4;
      if (tt + 3 < T_) {
        float4 v = make_float4(tile[tq + j * 4 + 0][cl], tile[tq + j * 4 + 1][cl],
                               tile[tq + j * 4 + 2][cl], tile[tq + j * 4 + 3][cl]);
        *(float4*)(Fr + tt) = v;
      } else {
#pragma unroll
        for (int e = 0; e < 4; ++e)
          if (tt + e < T_) Fr[tt + e] = tile[tq + j * 4 + e][cl];
      }
    }
  }
}

// ---------------- clean bf16 MFMA GEMM, 128x128x64, 2-phase pipeline -------
// D[m][t] = A[m][:] . B[t][:], A [M][K] bf16, B [b][TP][K] bf16.
// 4 waves (wm,wn in 2x2), wave owns 64m x 64t (4x4 16x16 frags), BK=64.
// Double-buffered LDS; ONE __syncthreads per K-step; stage k+1 before
// computing k so global_load_lds stays in flight under the MFMA cluster.
// EPI 0: O0 fp32 [t][128] = v+bias, Obf bf16 shadow            (bn1)
// EPI 1: prelu -> Obf bf16 [t][512], + masked GN stats          (pw)
// EPI 2: GN2-folded: res half RMW O0 fp32 + Obf shadow; skip RMW O1
// EPI 3: masked fp32 scatter O0[b][256][4000] = v+bias          (heads)
template <int EPI>
__global__ __launch_bounds__(256) void mm3(
    const unsigned short* __restrict__ A, const unsigned short* __restrict__ Bmat,
    int K, const float* __restrict__ bias,
    float* __restrict__ O0, float* __restrict__ O1, unsigned short* __restrict__ Obf,
    const float* __restrict__ alphaO, float* __restrict__ statsOut,
    const float* __restrict__ statsIn, float invN,
    const float* __restrict__ Uc, const float* __restrict__ Vc,
    const float* __restrict__ rb, const float* __restrict__ sb) {
  __shared__ unsigned short As[2][128 * 64];
  __shared__ unsigned short Bs[2][128 * 64];
  const int b = blockIdx.z;
  const int m0 = blockIdx.y * 128;
  const int t0 = blockIdx.x * 128;
  const int tid = threadIdx.x;
  const int lane = tid & 63;
  const int w = tid >> 6;
  const int wm = w >> 1, wn = w & 1;
  const int lt = lane & 15, lg = lane >> 4;
  const unsigned short* Ab = A + (size_t)m0 * K;
  const unsigned short* Bb = Bmat + ((size_t)b * TP_ + t0) * K;

  // staging: wave w covers rows [it*32 + w*8, +8) per issue; lane->row l>>3,
  // swizzled logical k-chunk (l&7)^(l>>3) (row&7 == l>>3). LDS dest linear.
  const int srow = w * 8 + (lane >> 3);
  const int skc  = ((lane & 7) ^ (lane >> 3)) * 8;

  f32x4 acc[4][4];
#pragma unroll
  for (int i = 0; i < 4; ++i)
#pragma unroll
    for (int j = 0; j < 4; ++j) acc[i][j] = (f32x4){0.f, 0.f, 0.f, 0.f};

  const int nk = K >> 6;
#pragma unroll
  for (int it = 0; it < 4; ++it) {
    g2lds16(Ab + (size_t)(it * 32 + srow) * K + skc, &As[0][(it * 32 + w * 8) * 64]);
    g2lds16(Bb + (size_t)(it * 32 + srow) * K + skc, &Bs[0][(it * 32 + w * 8) * 64]);
  }
  __syncthreads();

  for (int k = 0; k < nk; ++k) {
    const int cur = k & 1;
    if (k + 1 < nk) {
      const int kof = (k + 1) * 64;
#pragma unroll
      for (int it = 0; it < 4; ++it) {
        g2lds16(Ab + (size_t)(it * 32 + srow) * K + kof + skc,
                &As[cur ^ 1][(it * 32 + w * 8) * 64]);
        g2lds16(Bb + (size_t)(it * 32 + srow) * K + kof + skc,
                &Bs[cur ^ 1][(it * 32 + w * 8) * 64]);
      }
    }
#pragma unroll
    for (int ks = 0; ks < 2; ++ks) {
      s8v af[4], bf[4];
#pragma unroll
      for (int i = 0; i < 4; ++i) {
        const int R = wm * 64 + i * 16 + lt;
        af[i] = *(const s8v*)&As[cur][R * 64 + (((ks * 4 + lg) ^ (lt & 7)) * 8)];
      }
#pragma unroll
      for (int j = 0; j < 4; ++j) {
        const int R = wn * 64 + j * 16 + lt;
        bf[j] = *(const s8v*)&Bs[cur][R * 64 + (((ks * 4 + lg) ^ (lt & 7)) * 8)];
      }
#pragma unroll
      for (int i = 0; i < 4; ++i)
#pragma unroll
        for (int j = 0; j < 4; ++j)
          acc[i][j] = __builtin_amdgcn_mfma_f32_16x16x32_bf16(af[i], bf[j], acc[i][j], 0, 0, 0);
    }
    __syncthreads();
  }

  // ---- epilogues. D row m = m0 + wm*64 + i*16 + lg*4 + r,
  //                 D col t = t0 + wn*64 + j*16 + lt
  if constexpr (EPI == 0) {
#pragma unroll
    for (int i = 0; i < 4; ++i) {
      const int mg = m0 + wm * 64 + i * 16 + lg * 4;
      float4 bi = *(const float4*)(bias + mg);
#pragma unroll
      for (int j = 0; j < 4; ++j) {
        const int t = t0 + wn * 64 + j * 16 + lt;
        f32x4 v = acc[i][j];
        float nv[4] = {v[0] + bi.x, v[1] + bi.y, v[2] + bi.z, v[3] + bi.w};
        *(float4*)(O0 + ((size_t)b * TP_ + t) * 128 + mg) =
            make_float4(nv[0], nv[1], nv[2], nv[3]);
        u16x4 pk;
#pragma unroll
        for (int r = 0; r < 4; ++r) pk[r] = f2bf(nv[r]);
        *(u16x4*)(Obf + ((size_t)b * TP_ + t) * 128 + mg) = pk;
      }
    }
  } else if constexpr (EPI == 1) {
    const float aO = alphaO[0];
    float s1 = 0.f, s2 = 0.f;
#pragma unroll
    for (int i = 0; i < 4; ++i) {
      const int mg = m0 + wm * 64 + i * 16 + lg * 4;
      float4 bi = *(const float4*)(bias + mg);
      float bv[4] = {bi.x, bi.y, bi.z, bi.w};
#pragma unroll
      for (int j = 0; j < 4; ++j) {
        const int t = t0 + wn * 64 + j * 16 + lt;
        f32x4 v = acc[i][j];
        u16x4 pk;
#pragma unroll
        for (int r = 0; r < 4; ++r) {
          float f = v[r] + bv[r];
          f = f >= 0.f ? f : aO * f;
          pk[r] = f2bf(f);
        }
        *(u16x4*)(Obf + ((size_t)b * TP_ + t) * 512 + mg) = pk;
        if (t < T_) {
#pragma unroll
          for (int r = 0; r < 4; ++r) { float f = bf2f(pk[r]); s1 += f; s2 += f * f; }
        }
      }
    }
#pragma unroll
    for (int off = 32; off > 0; off >>= 1) {
      s1 += __shfl_xor(s1, off);
      s2 += __shfl_xor(s2, off);
    }
    if (lane == 0) {
      atomicAdd(&statsOut[b * 2 + 0], s1);
      atomicAdd(&statsOut[b * 2 + 1], s2);
    }
  } else if constexpr (EPI == 2) {
    const float mean = statsIn[b * 2] * invN;
    const float rsv = rsqrtf(statsIn[b * 2 + 1] * invN - mean * mean + 1e-8f);
#pragma unroll
    for (int i = 0; i < 4; ++i) {
      const int mgb = m0 + wm * 64 + i * 16 + lg * 4;   // 0..255
      float cc[4];
#pragma unroll
      for (int r = 0; r < 4; ++r) {
        const int mg = mgb + r;
        cc[r] = Vc[mg] - mean * rsv * Uc[mg] +
                ((m0 < 128) ? rb[mg] : sb[mg - 128]);
      }
#pragma unroll
      for (int j = 0; j < 4; ++j) {
        const int t = t0 + wn * 64 + j * 16 + lt;
        f32x4 v = acc[i][j];
        if (m0 < 128) {
          float* p = O0 + ((size_t)b * TP_ + t) * 128 + mgb;
          float4 old = *(float4*)p;
          float nv[4] = {old.x + rsv * v[0] + cc[0], old.y + rsv * v[1] + cc[1],
                         old.z + rsv * v[2] + cc[2], old.w + rsv * v[3] + cc[3]};
          *(float4*)p = make_float4(nv[0], nv[1], nv[2], nv[3]);
          u16x4 pk;
#pragma unroll
          for (int r = 0; r < 4; ++r) pk[r] = f2bf(nv[r]);
          *(u16x4*)(Obf + ((size_t)b * TP_ + t) * 128 + mgb) = pk;
        } else {
          float* p = O1 + ((size_t)b * TP_ + t) * 128 + (mgb - 128);
          float4 old = *(float4*)p;
          *(float4*)p = make_float4(old.x + rsv * v[0] + cc[0],
                                    old.y + rsv * v[1] + cc[1],
                                    old.z + rsv * v[2] + cc[2],
                                    old.w + rsv * v[3] + cc[3]);
        }
      }
    }
  } else {  // EPI 3: heads scatter to [b][256][4000]
#pragma unroll
    for (int i = 0; i < 4; ++i) {
      const int mg = m0 + wm * 64 + i * 16 + lg * 4;
#pragma unroll
      for (int j = 0; j < 4; ++j) {
        const int t = t0 + wn * 64 + j * 16 + lt;
        if (t < T_) {
          f32x4 v = acc[i][j];
#pragma unroll
          for (int r = 0; r < 4; ++r)
            O0[((size_t)b * 256 + mg + r) * T_ + t] = v[r] + bias[mg + r];
        }
      }
    }
  }
}

// ---------------- depthwise dilated conv, [t][h] layout --------------------
__global__ __launch_bounds__(256) void dw2(
    const unsigned short* __restrict__ Y, unsigned short* __restrict__ U,
    const float* __restrict__ dww, const float* __restrict__ dwb,
    const float* __restrict__ g1, const float* __restrict__ b1,
    const float* __restrict__ p2p, const float* __restrict__ sIn, float invN,
    float* __restrict__ sOut, int dil) {
  const int b = blockIdx.y;
  const int tid = threadIdx.x;
  const int hc = (tid & 63) * 8;
  const int tbase = blockIdx.x * 16 + (tid >> 6) * 4;

  const float mean = sIn[b * 2] * invN;
  const float rs = rsqrtf(sIn[b * 2 + 1] * invN - mean * mean + 1e-8f);
  float sA[8], oA[8], w0[8], w1[8], w2[8], bb[8];
#pragma unroll
  for (int j = 0; j < 8; ++j) {
    sA[j] = rs * g1[hc + j];
    oA[j] = b1[hc + j] - mean * sA[j];
    w0[j] = dww[(hc + j) * 3 + 0];
    w1[j] = dww[(hc + j) * 3 + 1];
    w2[j] = dww[(hc + j) * 3 + 2];
    bb[j] = dwb[hc + j];
  }
  const float alpha = p2p[0];
  const unsigned short* Yb = Y + (size_t)b * TP_ * 512;
  unsigned short* Ub = U + (size_t)b * TP_ * 512;
  float s1 = 0.f, s2 = 0.f;
#pragma unroll
  for (int i = 0; i < 4; ++i) {
    const int t = tbase + i;
    const int tm = t - dil, tp = t + dil;
    const bool vm = (tm >= 0), vp = (tp < T_);
    s8v xm = {0, 0, 0, 0, 0, 0, 0, 0};
    s8v xp = {0, 0, 0, 0, 0, 0, 0, 0};
    s8v x0 = *(const s8v*)(Yb + (size_t)t * 512 + hc);
    if (vm) xm = *(const s8v*)(Yb + (size_t)tm * 512 + hc);
    if (vp) xp = *(const s8v*)(Yb + (size_t)tp * 512 + hc);
    s8v out;
#pragma unroll
    for (int j = 0; j < 8; ++j) {
      float fm = vm ? (bf2f((unsigned short)xm[j]) * sA[j] + oA[j]) : 0.f;
      float f0 = bf2f((unsigned short)x0[j]) * sA[j] + oA[j];
      float fp = vp ? (bf2f((unsigned short)xp[j]) * sA[j] + oA[j]) : 0.f;
      float v = fmaf(w0[j], fm, fmaf(w1[j], f0, fmaf(w2[j], fp, bb[j])));
      v = v >= 0.f ? v : alpha * v;
      unsigned short u = f2bf(v);
      out[j] = (short)u;
      float f = bf2f(u);
      s1 += f; s2 += f * f;
    }
    *(s8v*)(Ub + (size_t)t * 512 + hc) = out;
  }
#pragma unroll
  for (int off = 32; off > 0; off >>= 1) {
    s1 += __shfl_xor(s1, off);
    s2 += __shfl_xor(s2, off);
  }
  if ((tid & 63) == 0) {
    atomicAdd(&sOut[b * 2 + 0], s1);
    atomicAdd(&sOut[b * 2 + 1], s2);
  }
}

// ---------------------------------------------------------------------------
extern "C" void kernel_launch(void* const* d_in, const int* in_sizes, int n_in,
                              void* d_out, int out_size, void* d_ws, size_t ws_size,
                              hipStream_t stream) {
  (void)in_sizes; (void)n_in; (void)out_size; (void)ws_size;
  const float* input = (const float*)d_in[0];
  const float* ln1_g = (const float*)d_in[1];
  const float* ln1_b = (const float*)d_in[2];
  const float* bn1_w = (const float*)d_in[3];
  const float* bn1_b = (const float*)d_in[4];
  const float* pw_w  = (const float*)d_in[5];
  const float* pw_b  = (const float*)d_in[6];
  const float* dw_w  = (const float*)d_in[7];
  const float* dw_b  = (const float*)d_in[8];
  const float* res_w = (const float*)d_in[9];
  const float* res_b = (const float*)d_in[10];
  const float* sk_w  = (const float*)d_in[11];
  const float* sk_b  = (const float*)d_in[12];
  const float* p1    = (const float*)d_in[13];
  const float* p2    = (const float*)d_in[14];
  const float* n1g   = (const float*)d_in[15];
  const float* n1b   = (const float*)d_in[16];
  const float* n2g   = (const float*)d_in[17];
  const float* n2b   = (const float*)d_in[18];
  const float* h1_p  = (const float*)d_in[19];
  const float* h1_w  = (const float*)d_in[20];
  const float* h1_b  = (const float*)d_in[21];
  const float* h2_p  = (const float*)d_in[22];
  const float* h2_w  = (const float*)d_in[23];
  const float* h2_b  = (const float*)d_in[24];

  float* out1 = (float*)d_out;
  float* out2 = out1 + 4096000;   // [4,256,4000]
  float* feat = out1 + 8192000;   // [4,128,4000]

  char* base = (char*)d_ws;
  float* OUTS  = (float*)base;                  base += (size_t)B_ * TP_ * 128 * 4;
  float* SKIP  = (float*)base;                  base += (size_t)B_ * TP_ * 128 * 4;
  float* OUT2  = (float*)base;                  base += (size_t)B_ * TP_ * 128 * 4;
  float* SKIP2 = (float*)base;                  base += (size_t)B_ * TP_ * 128 * 4;
  unsigned short* OUTbf  = (unsigned short*)base; base += (size_t)B_ * TP_ * 128 * 2;
  unsigned short* OUT2bf = (unsigned short*)base; base += (size_t)B_ * TP_ * 128 * 2;
  unsigned short* Ybuf = (unsigned short*)base; base += (size_t)B_ * TP_ * 512 * 2;
  unsigned short* Ubuf = (unsigned short*)base; base += (size_t)B_ * TP_ * 512 * 2;
  unsigned short* Xt   = (unsigned short*)base; base += (size_t)B_ * TP_ * 256 * 2;
  unsigned short* SKbf = (unsigned short*)base; base += (size_t)B_ * TP_ * 128 * 2;
  unsigned short* Wpw  = (unsigned short*)base; base += (size_t)32 * 512 * 128 * 2;
  unsigned short* Wg   = (unsigned short*)base; base += (size_t)32 * 256 * 512 * 2;
  unsigned short* Wbn  = (unsigned short*)base; base += (size_t)128 * 256 * 2;
  unsigned short* Wh1  = (unsigned short*)base; base += (size_t)256 * 128 * 2;
  unsigned short* Wh2  = (unsigned short*)base; base += (size_t)256 * 128 * 2;
  float* UVu   = (float*)base;                  base += (size_t)32 * 256 * 4;
  float* UVv   = (float*)base;                  base += (size_t)32 * 256 * 4;
  float* STATS = (float*)base;

  hipMemsetAsync(STATS, 0, 65 * 8 * sizeof(float), stream);
  hipMemsetAsync(SKIP, 0, (size_t)B_ * TP_ * 128 * sizeof(float), stream);

  const float invN_in = 1.0f / (256.0f * 4000.0f);
  const float invN_h  = 1.0f / (512.0f * 4000.0f);

  // weight prep
  cvt_bf<<<2048, 256, 0, stream>>>(pw_w, Wpw, 32 * 512 * 128);
  cvt_bf<<<128, 256, 0, stream>>>(bn1_w, Wbn, 128 * 256);
  cvt_bf<<<128, 256, 0, stream>>>(h1_w, Wh1, 256 * 128);
  cvt_bf<<<128, 256, 0, stream>>>(h2_w, Wh2, 256 * 128);
  fold_rs<<<32 * 256, 256, 0, stream>>>(res_w, sk_w, n2g, n2b, Wg, UVu, UVv);

  // input GN -> bf16 [t][256] -> bottleneck GEMM
  gn_stats<<<dim3(64, B_), 256, 0, stream>>>(input, STATS, 256 * T_);
  tin<<<dim3(63, 4, B_), 256, 0, stream>>>(input, Xt, ln1_g, ln1_b, STATS, invN_in);
  mm3<0><<<dim3(32, 1, B_), 256, 0, stream>>>(
      Wbn, Xt, 256, bn1_b, OUTS, nullptr, OUTbf, nullptr, nullptr,
      nullptr, 0.f, nullptr, nullptr, nullptr, nullptr);

  auto run_block = [&](int i, float* OS, float* SK, unsigned short* OSbf) {
    float* sA = STATS + (size_t)(1 + 2 * i) * 8;
    float* sB = STATS + (size_t)(2 + 2 * i) * 8;
    mm3<1><<<dim3(32, 4, B_), 256, 0, stream>>>(
        Wpw + (size_t)i * 512 * 128, OSbf, 128, pw_b + (size_t)i * 512,
        nullptr, nullptr, Ybuf, p1 + i, sA, nullptr, 0.f,
        nullptr, nullptr, nullptr, nullptr);
    dw2<<<dim3(250, B_), 256, 0, stream>>>(
        Ybuf, Ubuf, dw_w + (size_t)i * 512 * 3, dw_b + (size_t)i * 512,
        n1g + (size_t)i * 512, n1b + (size_t)i * 512, p2 + i, sA, invN_h, sB,
        1 << (i & 7));
    mm3<2><<<dim3(32, 2, B_), 256, 0, stream>>>(
        Wg + (size_t)i * 256 * 512, Ubuf, 512, nullptr, OS, SK, OSbf,
        nullptr, nullptr, sB, invN_h, UVu + (size_t)i * 256, UVv + (size_t)i * 256,
        res_b + (size_t)i * 128, sk_b + (size_t)i * 128);
  };

  for (int i = 0; i < 8; ++i) {
    run_block(i, OUTS, SKIP, OUTbf);
    if (i == 7) tfeat<<<dim3(63, 2, B_), 256, 0, stream>>>(OUTS, feat);
  }
  for (int i = 8; i < 16; ++i) run_block(i, OUTS, SKIP, OUTbf);

  hipMemcpyAsync(OUT2, OUTS, (size_t)B_ * TP_ * 128 * 4, hipMemcpyDeviceToDevice, stream);
  hipMemcpyAsync(OUT2bf, OUTbf, (size_t)B_ * TP_ * 128 * 2, hipMemcpyDeviceToDevice, stream);
  hipMemcpyAsync(SKIP2, SKIP, (size_t)B_ * TP_ * 128 * 4, hipMemcpyDeviceToDevice, stream);

  for (int i = 16; i < 24; ++i) run_block(i, OUTS, SKIP, OUTbf);
  for (int i = 24; i < 32; ++i) run_block(i, OUT2, SKIP2, OUT2bf);

  // heads: out = h_w @ prelu(skip) + h_b
  prelu_cvt<<<2048, 256, 0, stream>>>(SKIP, SKbf, h1_p, B_ * TP_ * 128);
  mm3<3><<<dim3(32, 2, B_), 256, 0, stream>>>(
      Wh1, SKbf, 128, h1_b, out1, nullptr, nullptr, nullptr, nullptr,
      nullptr, 0.f, nullptr, nullptr, nullptr, nullptr);
  prelu_cvt<<<2048, 256, 0, stream>>>(SKIP2, SKbf, h2_p, B_ * TP_ * 128);
  mm3<3><<<dim3(32, 2, B_), 256, 0, stream>>>(
      Wh2, SKbf, 128, h2_b, out2, nullptr, nullptr, nullptr, nullptr,
      nullptr, 0.f, nullptr, nullptr, nullptr, nullptr);
}

// Round 5
// 2485.598 us; speedup vs baseline: 2.4718x; 2.4718x over previous
//
#include <hip/hip_runtime.h>
#include <hip/hip_bf16.h>

// ---------------------------------------------------------------------------
// Conv-TasNet TCN, bf16-MFMA v4.
// mm5: 128x128x64 tile, 4 waves (2x2), single-buffer LDS (32KB), 2 barriers
// per K-step, clean bf16 operands staged via global_load_lds_dwordx4 with
// both-sides XOR swizzle. All stats reductions: ONE device atomic per block.
// GN folded as affine (GN1 into dw, GN2 into res/skip weights).
// Layout: activations [B][TP=4096][C] time-major.
// ---------------------------------------------------------------------------

#define T_  4000
#define TP_ 4096
#define B_  4

typedef __attribute__((ext_vector_type(8))) short  s8v;
typedef __attribute__((ext_vector_type(4))) float  f32x4;
typedef __attribute__((ext_vector_type(4))) unsigned short u16x4;

__device__ __forceinline__ float bf2f(unsigned short u) {
  unsigned int i = ((unsigned int)u) << 16;
  float f; __builtin_memcpy(&f, &i, 4); return f;
}
__device__ __forceinline__ unsigned short f2bf(float f) {
  unsigned int i; __builtin_memcpy(&i, &f, 4);
  unsigned int r = i + 0x7fffu + ((i >> 16) & 1u);
  return (unsigned short)(r >> 16);
}

__device__ __forceinline__ void g2lds16(const void* g, void* l) {
  __builtin_amdgcn_global_load_lds(
      (const __attribute__((address_space(1))) unsigned int*)g,
      (__attribute__((address_space(3))) unsigned int*)l, 16, 0, 0);
}

// ---------------- per-sample sum/sumsq over contiguous [C*T] ---------------
__global__ __launch_bounds__(256) void gn_stats(const float* __restrict__ X,
                                                float* __restrict__ statsOut, int n) {
  const int b = blockIdx.y;
  const float4* xp = (const float4*)(X + (size_t)b * n);
  const int n4 = n >> 2;
  float s1 = 0.f, s2 = 0.f;
  for (int idx = blockIdx.x * 256 + threadIdx.x; idx < n4; idx += gridDim.x * 256) {
    float4 v = xp[idx];
    s1 += v.x + v.y + v.z + v.w;
    s2 += v.x * v.x + v.y * v.y + v.z * v.z + v.w * v.w;
  }
#pragma unroll
  for (int off = 32; off > 0; off >>= 1) {
    s1 += __shfl_xor(s1, off);
    s2 += __shfl_xor(s2, off);
  }
  __shared__ float red[8];
  const int lane = threadIdx.x & 63, wv = threadIdx.x >> 6;
  if (lane == 0) { red[wv] = s1; red[4 + wv] = s2; }
  __syncthreads();
  if (threadIdx.x == 0) {
    atomicAdd(&statsOut[b * 2 + 0], red[0] + red[1] + red[2] + red[3]);
    atomicAdd(&statsOut[b * 2 + 1], red[4] + red[5] + red[6] + red[7]);
  }
}

// ---------------- weight prep ----------------------------------------------
__global__ __launch_bounds__(256) void cvt_bf(const float* __restrict__ s,
                                              unsigned short* __restrict__ d, int n) {
  for (int i = blockIdx.x * 256 + threadIdx.x; i < n; i += gridDim.x * 256)
    d[i] = f2bf(s[i]);
}

// GN2 fold: Wg[i][m][h] = bf16(w[m,h]*g2[i,h]); u=sum(w*g2); v=sum(w*b2)
__global__ __launch_bounds__(256) void fold_rs(
    const float* __restrict__ rw, const float* __restrict__ sw,
    const float* __restrict__ g2a, const float* __restrict__ b2a,
    unsigned short* __restrict__ Wg, float* __restrict__ Ucb,
    float* __restrict__ Vcb) {
  const int row = blockIdx.x;                 // i*256 + m
  const int i = row >> 8, m = row & 255;
  const float* src = (m < 128) ? rw + ((size_t)i * 128 + m) * 512
                               : sw + ((size_t)i * 128 + (m - 128)) * 512;
  const float* g = g2a + (size_t)i * 512;
  const float* bb = b2a + (size_t)i * 512;
  unsigned short* dst = Wg + (size_t)row * 512;
  float u = 0.f, v = 0.f;
  for (int h = threadIdx.x; h < 512; h += 256) {
    float wgt = src[h] * g[h];
    dst[h] = f2bf(wgt);
    u += wgt; v += src[h] * bb[h];
  }
#pragma unroll
  for (int off = 32; off > 0; off >>= 1) {
    u += __shfl_xor(u, off);
    v += __shfl_xor(v, off);
  }
  __shared__ float red[8];
  const int lane = threadIdx.x & 63, wv = threadIdx.x >> 6;
  if (lane == 0) { red[wv] = u; red[4 + wv] = v; }
  __syncthreads();
  if (threadIdx.x == 0) {
    Ucb[row] = red[0] + red[1] + red[2] + red[3];
    Vcb[row] = red[4] + red[5] + red[6] + red[7];
  }
}

// prelu + bf16 convert (heads input prep)
__global__ __launch_bounds__(256) void prelu_cvt(const float* __restrict__ S,
                                                 unsigned short* __restrict__ D,
                                                 const float* __restrict__ ap, int n) {
  const float a = ap[0];
  for (int i = blockIdx.x * 256 + threadIdx.x; i < n; i += gridDim.x * 256) {
    float v = S[i];
    v = v >= 0.f ? v : a * v;
    D[i] = f2bf(v);
  }
}

// ---------------- input transpose + GN affine + bf16 -----------------------
__global__ __launch_bounds__(256) void tin(const float* __restrict__ X,
                                           unsigned short* __restrict__ Xt,
                                           const float* __restrict__ g,
                                           const float* __restrict__ bt,
                                           const float* __restrict__ sIn, float invN) {
  const int b = blockIdx.z, c0 = blockIdx.y * 64, t0 = blockIdx.x * 64;
  __shared__ float tile[64][65];
  const int tid = threadIdx.x;
  const float mean = sIn[b * 2] * invN;
  const float rs = rsqrtf(sIn[b * 2 + 1] * invN - mean * mean + 1e-8f);
  {
    const int cl = tid >> 2, tq = (tid & 3) * 16;
    const float* Xr = X + ((size_t)b * 256 + c0 + cl) * T_;
#pragma unroll
    for (int j = 0; j < 4; ++j) {
      int tt = t0 + tq + j * 4;
      float4 v;
      if (tt + 3 < T_) v = *(const float4*)(Xr + tt);
      else {
        v.x = (tt + 0 < T_) ? Xr[tt + 0] : 0.f;
        v.y = (tt + 1 < T_) ? Xr[tt + 1] : 0.f;
        v.z = (tt + 2 < T_) ? Xr[tt + 2] : 0.f;
        v.w = (tt + 3 < T_) ? Xr[tt + 3] : 0.f;
      }
      tile[cl][tq + j * 4 + 0] = v.x; tile[cl][tq + j * 4 + 1] = v.y;
      tile[cl][tq + j * 4 + 2] = v.z; tile[cl][tq + j * 4 + 3] = v.w;
    }
  }
  __syncthreads();
  {
    const int tl = tid >> 2, cq = (tid & 3) * 16;
    const int t = t0 + tl;
    if (t < T_) {
      unsigned short* dst = Xt + ((size_t)b * TP_ + t) * 256 + c0 + cq;
      s8v u0, u1;
#pragma unroll
      for (int j = 0; j < 16; ++j) {
        int c = c0 + cq + j;
        float sc = rs * g[c];
        float oc = bt[c] - mean * sc;
        unsigned short uu = f2bf(tile[cq + j][tl] * sc + oc);
        if (j < 8) u0[j] = (short)uu; else u1[j - 8] = (short)uu;
      }
      *(s8v*)dst = u0;
      *(s8v*)(dst + 8) = u1;
    }
  }
}

// ---------------- feature_r: OUTS [t][128] fp32 -> feat [128][t] fp32 ------
__global__ __launch_bounds__(256) void tfeat(const float* __restrict__ O,
                                             float* __restrict__ F) {
  const int b = blockIdx.z, c0 = blockIdx.y * 64, t0 = blockIdx.x * 64;
  __shared__ float tile[64][65];
  const int tid = threadIdx.x;
  {
    const int tr = tid >> 2, cq = (tid & 3) * 16;
    const int t = t0 + tr;
#pragma unroll
    for (int j = 0; j < 4; ++j) {
      float4 v = make_float4(0.f, 0.f, 0.f, 0.f);
      if (t < T_) v = *(const float4*)(O + ((size_t)b * TP_ + t) * 128 + c0 + cq + j * 4);
      tile[tr][cq + j * 4 + 0] = v.x; tile[tr][cq + j * 4 + 1] = v.y;
      tile[tr][cq + j * 4 + 2] = v.z; tile[tr][cq + j * 4 + 3] = v.w;
    }
  }
  __syncthreads();
  {
    const int cl = tid >> 2, tq = (tid & 3) * 16;
    float* Fr = F + ((size_t)b * 128 + c0 + cl) * T_;
#pragma unroll
    for (int j = 0; j < 4; ++j) {
      int tt = t0 + tq + j * 4;
      if (tt + 3 < T_) {
        float4 v = make_float4(tile[tq + j * 4 + 0][cl], tile[tq + j * 4 + 1][cl],
                               tile[tq + j * 4 + 2][cl], tile[tq + j * 4 + 3][cl]);
        *(float4*)(Fr + tt) = v;
      } else {
#pragma unroll
        for (int e = 0; e < 4; ++e)
          if (tt + e < T_) Fr[tt + e] = tile[tq + j * 4 + e][cl];
      }
    }
  }
}

// ---------------- clean bf16 MFMA GEMM, 128x128x64, single-buffer ----------
// D[m][t] = A[m][:] . B[t][:], A [M][K] bf16, B [b][TP][K] bf16.
// 4 waves (2x2), wave owns 64m x 64t (4x4 16x16x32 frags).
// EPI 0: O0 fp32 [t][128] = v+bias, Obf bf16 shadow            (bn1)
// EPI 1: prelu -> Obf bf16 [t][512], + masked GN stats          (pw)
// EPI 2: GN2-folded; blockIdx.y==0: res RMW O0 + Obf shadow; y==1: skip RMW O1
// EPI 3: masked fp32 scatter O0[b][256][4000] = v+bias          (heads)
template <int EPI>
__global__ __launch_bounds__(256) void mm5(
    const unsigned short* __restrict__ A, const unsigned short* __restrict__ Bmat,
    int K, const float* __restrict__ bias,
    float* __restrict__ O0, float* __restrict__ O1, unsigned short* __restrict__ Obf,
    const float* __restrict__ alphaO, float* __restrict__ statsOut,
    const float* __restrict__ statsIn, float invN,
    const float* __restrict__ Uc, const float* __restrict__ Vc,
    const float* __restrict__ rb, const float* __restrict__ sb) {
  __shared__ unsigned short As[128 * 64];
  __shared__ unsigned short Bs[128 * 64];
  __shared__ float redw[8];
  const int b = blockIdx.z;
  const int m0 = blockIdx.y * 128;
  const int t0 = blockIdx.x * 128;
  const int tid = threadIdx.x;
  const int lane = tid & 63;
  const int w = tid >> 6;
  const int wm = w >> 1, wn = w & 1;
  const int lt = lane & 15, lg = lane >> 4;
  const unsigned short* Ab = A + (size_t)m0 * K;
  const unsigned short* Bb = Bmat + ((size_t)b * TP_ + t0) * K;

  // staging: chunk = 8 rows x 64k = 1KB; lane l -> row (l>>3),
  // swizzled logical k-chunk (l&7)^(l>>3); LDS dest linear.
  const int srow8 = lane >> 3;
  const int skc   = ((lane & 7) ^ (lane >> 3)) * 8;

  f32x4 acc[4][4];
#pragma unroll
  for (int i = 0; i < 4; ++i)
#pragma unroll
    for (int j = 0; j < 4; ++j) acc[i][j] = (f32x4){0.f, 0.f, 0.f, 0.f};

  for (int k0 = 0; k0 < K; k0 += 64) {
#pragma unroll
    for (int c = 0; c < 4; ++c) {
      const int ch = w * 4 + c;   // 0..15, rows ch*8..+8
      g2lds16(Ab + (size_t)(ch * 8 + srow8) * K + k0 + skc, &As[ch * 512]);
      g2lds16(Bb + (size_t)(ch * 8 + srow8) * K + k0 + skc, &Bs[ch * 512]);
    }
    __syncthreads();
#pragma unroll
    for (int ks = 0; ks < 2; ++ks) {
      s8v bf[4];
#pragma unroll
      for (int j = 0; j < 4; ++j) {
        const int R = wn * 64 + j * 16 + lt;
        bf[j] = *(const s8v*)&Bs[R * 64 + (((ks * 4 + lg) ^ (lt & 7)) * 8)];
      }
#pragma unroll
      for (int i = 0; i < 4; ++i) {
        const int R = wm * 64 + i * 16 + lt;
        s8v af = *(const s8v*)&As[R * 64 + (((ks * 4 + lg) ^ (lt & 7)) * 8)];
#pragma unroll
        for (int j = 0; j < 4; ++j)
          acc[i][j] = __builtin_amdgcn_mfma_f32_16x16x32_bf16(af, bf[j], acc[i][j], 0, 0, 0);
      }
    }
    __syncthreads();
  }

  // ---- epilogues. D row m = m0 + wm*64 + i*16 + lg*4 + r,
  //                 D col t = t0 + wn*64 + j*16 + lt
  if constexpr (EPI == 0) {
#pragma unroll
    for (int i = 0; i < 4; ++i) {
      const int mg = m0 + wm * 64 + i * 16 + lg * 4;
      float4 bi = *(const float4*)(bias + mg);
#pragma unroll
      for (int j = 0; j < 4; ++j) {
        const int t = t0 + wn * 64 + j * 16 + lt;
        f32x4 v = acc[i][j];
        float nv[4] = {v[0] + bi.x, v[1] + bi.y, v[2] + bi.z, v[3] + bi.w};
        *(float4*)(O0 + ((size_t)b * TP_ + t) * 128 + mg) =
            make_float4(nv[0], nv[1], nv[2], nv[3]);
        u16x4 pk;
#pragma unroll
        for (int r = 0; r < 4; ++r) pk[r] = f2bf(nv[r]);
        *(u16x4*)(Obf + ((size_t)b * TP_ + t) * 128 + mg) = pk;
      }
    }
  } else if constexpr (EPI == 1) {
    const float aO = alphaO[0];
    float s1 = 0.f, s2 = 0.f;
#pragma unroll
    for (int i = 0; i < 4; ++i) {
      const int mg = m0 + wm * 64 + i * 16 + lg * 4;
      float4 bi = *(const float4*)(bias + mg);
      float bv[4] = {bi.x, bi.y, bi.z, bi.w};
#pragma unroll
      for (int j = 0; j < 4; ++j) {
        const int t = t0 + wn * 64 + j * 16 + lt;
        f32x4 v = acc[i][j];
        u16x4 pk;
#pragma unroll
        for (int r = 0; r < 4; ++r) {
          float f = v[r] + bv[r];
          f = f >= 0.f ? f : aO * f;
          pk[r] = f2bf(f);
        }
        *(u16x4*)(Obf + ((size_t)b * TP_ + t) * 512 + mg) = pk;
        if (t < T_) {
#pragma unroll
          for (int r = 0; r < 4; ++r) { float f = bf2f(pk[r]); s1 += f; s2 += f * f; }
        }
      }
    }
#pragma unroll
    for (int off = 32; off > 0; off >>= 1) {
      s1 += __shfl_xor(s1, off);
      s2 += __shfl_xor(s2, off);
    }
    if (lane == 0) { redw[w] = s1; redw[4 + w] = s2; }
    __syncthreads();
    if (tid == 0) {
      atomicAdd(&statsOut[b * 2 + 0], redw[0] + redw[1] + redw[2] + redw[3]);
      atomicAdd(&statsOut[b * 2 + 1], redw[4] + redw[5] + redw[6] + redw[7]);
    }
  } else if constexpr (EPI == 2) {
    const float mean = statsIn[b * 2] * invN;
    const float rsv = rsqrtf(statsIn[b * 2 + 1] * invN - mean * mean + 1e-8f);
    const bool isRes = (m0 == 0);
#pragma unroll
    for (int i = 0; i < 4; ++i) {
      const int ml = wm * 64 + i * 16 + lg * 4;   // 0..127 local
      float cc[4];
#pragma unroll
      for (int r = 0; r < 4; ++r) {
        const int mgG = m0 + ml + r;              // 0..255 (Uc/Vc index)
        cc[r] = Vc[mgG] - mean * rsv * Uc[mgG] + (isRes ? rb[ml + r] : sb[ml + r]);
      }
#pragma unroll
      for (int j = 0; j < 4; ++j) {
        const int t = t0 + wn * 64 + j * 16 + lt;
        f32x4 v = acc[i][j];
        if (isRes) {
          float* p = O0 + ((size_t)b * TP_ + t) * 128 + ml;
          float4 old = *(float4*)p;
          float nv[4] = {old.x + rsv * v[0] + cc[0], old.y + rsv * v[1] + cc[1],
                         old.z + rsv * v[2] + cc[2], old.w + rsv * v[3] + cc[3]};
          *(float4*)p = make_float4(nv[0], nv[1], nv[2], nv[3]);
          u16x4 pk;
#pragma unroll
          for (int r = 0; r < 4; ++r) pk[r] = f2bf(nv[r]);
          *(u16x4*)(Obf + ((size_t)b * TP_ + t) * 128 + ml) = pk;
        } else {
          float* p = O1 + ((size_t)b * TP_ + t) * 128 + ml;
          float4 old = *(float4*)p;
          *(float4*)p = make_float4(old.x + rsv * v[0] + cc[0],
                                    old.y + rsv * v[1] + cc[1],
                                    old.z + rsv * v[2] + cc[2],
                                    old.w + rsv * v[3] + cc[3]);
        }
      }
    }
  } else {  // EPI 3: heads scatter to [b][256][4000]
#pragma unroll
    for (int i = 0; i < 4; ++i) {
      const int mg = m0 + wm * 64 + i * 16 + lg * 4;
#pragma unroll
      for (int j = 0; j < 4; ++j) {
        const int t = t0 + wn * 64 + j * 16 + lt;
        if (t < T_) {
          f32x4 v = acc[i][j];
#pragma unroll
          for (int r = 0; r < 4; ++r)
            O0[((size_t)b * 256 + mg + r) * T_ + t] = v[r] + bias[mg + r];
        }
      }
    }
  }
}

// ---------------- depthwise dilated conv, [t][h] layout --------------------
__global__ __launch_bounds__(256) void dw2(
    const unsigned short* __restrict__ Y, unsigned short* __restrict__ U,
    const float* __restrict__ dww, const float* __restrict__ dwb,
    const float* __restrict__ g1, const float* __restrict__ b1,
    const float* __restrict__ p2p, const float* __restrict__ sIn, float invN,
    float* __restrict__ sOut, int dil) {
  const int b = blockIdx.y;
  const int tid = threadIdx.x;
  const int hc = (tid & 63) * 8;
  const int tbase = blockIdx.x * 16 + (tid >> 6) * 4;

  const float mean = sIn[b * 2] * invN;
  const float rs = rsqrtf(sIn[b * 2 + 1] * invN - mean * mean + 1e-8f);
  float sA[8], oA[8], w0[8], w1[8], w2[8], bb[8];
#pragma unroll
  for (int j = 0; j < 8; ++j) {
    sA[j] = rs * g1[hc + j];
    oA[j] = b1[hc + j] - mean * sA[j];
    w0[j] = dww[(hc + j) * 3 + 0];
    w1[j] = dww[(hc + j) * 3 + 1];
    w2[j] = dww[(hc + j) * 3 + 2];
    bb[j] = dwb[hc + j];
  }
  const float alpha = p2p[0];
  const unsigned short* Yb = Y + (size_t)b * TP_ * 512;
  unsigned short* Ub = U + (size_t)b * TP_ * 512;
  float s1 = 0.f, s2 = 0.f;
#pragma unroll
  for (int i = 0; i < 4; ++i) {
    const int t = tbase + i;
    const int tm = t - dil, tp = t + dil;
    const bool vm = (tm >= 0), vp = (tp < T_);
    s8v xm = {0, 0, 0, 0, 0, 0, 0, 0};
    s8v xp = {0, 0, 0, 0, 0, 0, 0, 0};
    s8v x0 = *(const s8v*)(Yb + (size_t)t * 512 + hc);
    if (vm) xm = *(const s8v*)(Yb + (size_t)tm * 512 + hc);
    if (vp) xp = *(const s8v*)(Yb + (size_t)tp * 512 + hc);
    s8v out;
#pragma unroll
    for (int j = 0; j < 8; ++j) {
      float fm = vm ? (bf2f((unsigned short)xm[j]) * sA[j] + oA[j]) : 0.f;
      float f0 = bf2f((unsigned short)x0[j]) * sA[j] + oA[j];
      float fp = vp ? (bf2f((unsigned short)xp[j]) * sA[j] + oA[j]) : 0.f;
      float v = fmaf(w0[j], fm, fmaf(w1[j], f0, fmaf(w2[j], fp, bb[j])));
      v = v >= 0.f ? v : alpha * v;
      unsigned short u = f2bf(v);
      out[j] = (short)u;
      float f = bf2f(u);
      s1 += f; s2 += f * f;
    }
    *(s8v*)(Ub + (size_t)t * 512 + hc) = out;
  }
#pragma unroll
  for (int off = 32; off > 0; off >>= 1) {
    s1 += __shfl_xor(s1, off);
    s2 += __shfl_xor(s2, off);
  }
  __shared__ float red[8];
  const int lane = tid & 63, wv = tid >> 6;
  if (lane == 0) { red[wv] = s1; red[4 + wv] = s2; }
  __syncthreads();
  if (tid == 0) {
    atomicAdd(&sOut[b * 2 + 0], red[0] + red[1] + red[2] + red[3]);
    atomicAdd(&sOut[b * 2 + 1], red[4] + red[5] + red[6] + red[7]);
  }
}

// ---------------------------------------------------------------------------
extern "C" void kernel_launch(void* const* d_in, const int* in_sizes, int n_in,
                              void* d_out, int out_size, void* d_ws, size_t ws_size,
                              hipStream_t stream) {
  (void)in_sizes; (void)n_in; (void)out_size; (void)ws_size;
  const float* input = (const float*)d_in[0];
  const float* ln1_g = (const float*)d_in[1];
  const float* ln1_b = (const float*)d_in[2];
  const float* bn1_w = (const float*)d_in[3];
  const float* bn1_b = (const float*)d_in[4];
  const float* pw_w  = (const float*)d_in[5];
  const float* pw_b  = (const float*)d_in[6];
  const float* dw_w  = (const float*)d_in[7];
  const float* dw_b  = (const float*)d_in[8];
  const float* res_w = (const float*)d_in[9];
  const float* res_b = (const float*)d_in[10];
  const float* sk_w  = (const float*)d_in[11];
  const float* sk_b  = (const float*)d_in[12];
  const float* p1    = (const float*)d_in[13];
  const float* p2    = (const float*)d_in[14];
  const float* n1g   = (const float*)d_in[15];
  const float* n1b   = (const float*)d_in[16];
  const float* n2g   = (const float*)d_in[17];
  const float* n2b   = (const float*)d_in[18];
  const float* h1_p  = (const float*)d_in[19];
  const float* h1_w  = (const float*)d_in[20];
  const float* h1_b  = (const float*)d_in[21];
  const float* h2_p  = (const float*)d_in[22];
  const float* h2_w  = (const float*)d_in[23];
  const float* h2_b  = (const float*)d_in[24];

  float* out1 = (float*)d_out;
  float* out2 = out1 + 4096000;   // [4,256,4000]
  float* feat = out1 + 8192000;   // [4,128,4000]

  char* base = (char*)d_ws;
  float* OUTS  = (float*)base;                  base += (size_t)B_ * TP_ * 128 * 4;
  float* SKIP  = (float*)base;                  base += (size_t)B_ * TP_ * 128 * 4;
  float* OUT2  = (float*)base;                  base += (size_t)B_ * TP_ * 128 * 4;
  float* SKIP2 = (float*)base;                  base += (size_t)B_ * TP_ * 128 * 4;
  unsigned short* OUTbf  = (unsigned short*)base; base += (size_t)B_ * TP_ * 128 * 2;
  unsigned short* OUT2bf = (unsigned short*)base; base += (size_t)B_ * TP_ * 128 * 2;
  unsigned short* Ybuf = (unsigned short*)base; base += (size_t)B_ * TP_ * 512 * 2;
  unsigned short* Ubuf = (unsigned short*)base; base += (size_t)B_ * TP_ * 512 * 2;
  unsigned short* Xt   = (unsigned short*)base; base += (size_t)B_ * TP_ * 256 * 2;
  unsigned short* SKbf = (unsigned short*)base; base += (size_t)B_ * TP_ * 128 * 2;
  unsigned short* Wpw  = (unsigned short*)base; base += (size_t)32 * 512 * 128 * 2;
  unsigned short* Wg   = (unsigned short*)base; base += (size_t)32 * 256 * 512 * 2;
  unsigned short* Wbn  = (unsigned short*)base; base += (size_t)128 * 256 * 2;
  unsigned short* Wh1  = (unsigned short*)base; base += (size_t)256 * 128 * 2;
  unsigned short* Wh2  = (unsigned short*)base; base += (size_t)256 * 128 * 2;
  float* UVu   = (float*)base;                  base += (size_t)32 * 256 * 4;
  float* UVv   = (float*)base;                  base += (size_t)32 * 256 * 4;
  float* STATS = (float*)base;

  hipMemsetAsync(STATS, 0, 65 * 8 * sizeof(float), stream);
  hipMemsetAsync(SKIP, 0, (size_t)B_ * TP_ * 128 * sizeof(float), stream);

  const float invN_in = 1.0f / (256.0f * 4000.0f);
  const float invN_h  = 1.0f / (512.0f * 4000.0f);

  // weight prep
  cvt_bf<<<2048, 256, 0, stream>>>(pw_w, Wpw, 32 * 512 * 128);
  cvt_bf<<<128, 256, 0, stream>>>(bn1_w, Wbn, 128 * 256);
  cvt_bf<<<128, 256, 0, stream>>>(h1_w, Wh1, 256 * 128);
  cvt_bf<<<128, 256, 0, stream>>>(h2_w, Wh2, 256 * 128);
  fold_rs<<<32 * 256, 256, 0, stream>>>(res_w, sk_w, n2g, n2b, Wg, UVu, UVv);

  // input GN -> bf16 [t][256] -> bottleneck GEMM
  gn_stats<<<dim3(64, B_), 256, 0, stream>>>(input, STATS, 256 * T_);
  tin<<<dim3(63, 4, B_), 256, 0, stream>>>(input, Xt, ln1_g, ln1_b, STATS, invN_in);
  mm5<0><<<dim3(32, 1, B_), 256, 0, stream>>>(
      Wbn, Xt, 256, bn1_b, OUTS, nullptr, OUTbf, nullptr, nullptr,
      nullptr, 0.f, nullptr, nullptr, nullptr, nullptr);

  auto run_block = [&](int i, float* OS, float* SK, unsigned short* OSbf) {
    float* sA = STATS + (size_t)(1 + 2 * i) * 8;
    float* sB = STATS + (size_t)(2 + 2 * i) * 8;
    mm5<1><<<dim3(32, 4, B_), 256, 0, stream>>>(
        Wpw + (size_t)i * 512 * 128, OSbf, 128, pw_b + (size_t)i * 512,
        nullptr, nullptr, Ybuf, p1 + i, sA, nullptr, 0.f,
        nullptr, nullptr, nullptr, nullptr);
    dw2<<<dim3(250, B_), 256, 0, stream>>>(
        Ybuf, Ubuf, dw_w + (size_t)i * 512 * 3, dw_b + (size_t)i * 512,
        n1g + (size_t)i * 512, n1b + (size_t)i * 512, p2 + i, sA, invN_h, sB,
        1 << (i & 7));
    mm5<2><<<dim3(32, 2, B_), 256, 0, stream>>>(
        Wg + (size_t)i * 256 * 512, Ubuf, 512, nullptr, OS, SK, OSbf,
        nullptr, nullptr, sB, invN_h, UVu + (size_t)i * 256, UVv + (size_t)i * 256,
        res_b + (size_t)i * 128, sk_b + (size_t)i * 128);
  };

  for (int i = 0; i < 8; ++i) {
    run_block(i, OUTS, SKIP, OUTbf);
    if (i == 7) tfeat<<<dim3(63, 2, B_), 256, 0, stream>>>(OUTS, feat);
  }
  for (int i = 8; i < 16; ++i) run_block(i, OUTS, SKIP, OUTbf);

  hipMemcpyAsync(OUT2, OUTS, (size_t)B_ * TP_ * 128 * 4, hipMemcpyDeviceToDevice, stream);
  hipMemcpyAsync(OUT2bf, OUTbf, (size_t)B_ * TP_ * 128 * 2, hipMemcpyDeviceToDevice, stream);
  hipMemcpyAsync(SKIP2, SKIP, (size_t)B_ * TP_ * 128 * 4, hipMemcpyDeviceToDevice, stream);

  for (int i = 16; i < 24; ++i) run_block(i, OUTS, SKIP, OUTbf);
  for (int i = 24; i < 32; ++i) run_block(i, OUT2, SKIP2, OUT2bf);

  // heads: out = h_w @ prelu(skip) + h_b
  prelu_cvt<<<2048, 256, 0, stream>>>(SKIP, SKbf, h1_p, B_ * TP_ * 128);
  mm5<3><<<dim3(32, 2, B_), 256, 0, stream>>>(
      Wh1, SKbf, 128, h1_b, out1, nullptr, nullptr, nullptr, nullptr,
      nullptr, 0.f, nullptr, nullptr, nullptr, nullptr);
  prelu_cvt<<<2048, 256, 0, stream>>>(SKIP2, SKbf, h2_p, B_ * TP_ * 128);
  mm5<3><<<dim3(32, 2, B_), 256, 0, stream>>>(
      Wh2, SKbf, 128, h2_b, out2, nullptr, nullptr, nullptr, nullptr,
      nullptr, 0.f, nullptr, nullptr, nullptr, nullptr);
}

// Round 6
// 2141.402 us; speedup vs baseline: 2.8691x; 1.1607x over previous
//
#include <hip/hip_runtime.h>
#include <hip/hip_bf16.h>

// ---------------------------------------------------------------------------
// Conv-TasNet TCN, bf16-MFMA v5.
// mm6: 128m x TNt x 64k tile (TN=128 or 64), 4 waves, single-buffer LDS,
// clean bf16 operands staged via global_load_lds_dwordx4 + XOR swizzle.
// Branch pairing: blocks 16-23 (branch1) and 24-31 (branch2) run in the SAME
// launches (blockIdx.z 0..7). Y/U are 8-slot buffers (slots 4-7 = branch2).
// Fused: feat into block-7 rs, branch fork into block-15 rs, heads paired.
// ---------------------------------------------------------------------------

#define T_  4000
#define TP_ 4096
#define B_  4

typedef __attribute__((ext_vector_type(8))) short  s8v;
typedef __attribute__((ext_vector_type(4))) float  f32x4;
typedef __attribute__((ext_vector_type(4))) unsigned short u16x4;

__device__ __forceinline__ float bf2f(unsigned short u) {
  unsigned int i = ((unsigned int)u) << 16;
  float f; __builtin_memcpy(&f, &i, 4); return f;
}
__device__ __forceinline__ unsigned short f2bf(float f) {
  unsigned int i; __builtin_memcpy(&i, &f, 4);
  unsigned int r = i + 0x7fffu + ((i >> 16) & 1u);
  return (unsigned short)(r >> 16);
}

__device__ __forceinline__ void g2lds16(const void* g, void* l) {
  __builtin_amdgcn_global_load_lds(
      (const __attribute__((address_space(1))) unsigned int*)g,
      (__attribute__((address_space(3))) unsigned int*)l, 16, 0, 0);
}

// ---------------- per-sample sum/sumsq over contiguous [C*T] ---------------
__global__ __launch_bounds__(256) void gn_stats(const float* __restrict__ X,
                                                float* __restrict__ statsOut, int n) {
  const int b = blockIdx.y;
  const float4* xp = (const float4*)(X + (size_t)b * n);
  const int n4 = n >> 2;
  float s1 = 0.f, s2 = 0.f;
  for (int idx = blockIdx.x * 256 + threadIdx.x; idx < n4; idx += gridDim.x * 256) {
    float4 v = xp[idx];
    s1 += v.x + v.y + v.z + v.w;
    s2 += v.x * v.x + v.y * v.y + v.z * v.z + v.w * v.w;
  }
#pragma unroll
  for (int off = 32; off > 0; off >>= 1) {
    s1 += __shfl_xor(s1, off);
    s2 += __shfl_xor(s2, off);
  }
  __shared__ float red[8];
  const int lane = threadIdx.x & 63, wv = threadIdx.x >> 6;
  if (lane == 0) { red[wv] = s1; red[4 + wv] = s2; }
  __syncthreads();
  if (threadIdx.x == 0) {
    atomicAdd(&statsOut[b * 2 + 0], red[0] + red[1] + red[2] + red[3]);
    atomicAdd(&statsOut[b * 2 + 1], red[4] + red[5] + red[6] + red[7]);
  }
}

// ---------------- weight prep ----------------------------------------------
__global__ __launch_bounds__(256) void cvt_bf(const float* __restrict__ s,
                                              unsigned short* __restrict__ d, int n) {
  for (int i = blockIdx.x * 256 + threadIdx.x; i < n; i += gridDim.x * 256)
    d[i] = f2bf(s[i]);
}

__global__ __launch_bounds__(256) void fold_rs(
    const float* __restrict__ rw, const float* __restrict__ sw,
    const float* __restrict__ g2a, const float* __restrict__ b2a,
    unsigned short* __restrict__ Wg, float* __restrict__ Ucb,
    float* __restrict__ Vcb) {
  const int row = blockIdx.x;                 // i*256 + m
  const int i = row >> 8, m = row & 255;
  const float* src = (m < 128) ? rw + ((size_t)i * 128 + m) * 512
                               : sw + ((size_t)i * 128 + (m - 128)) * 512;
  const float* g = g2a + (size_t)i * 512;
  const float* bb = b2a + (size_t)i * 512;
  unsigned short* dst = Wg + (size_t)row * 512;
  float u = 0.f, v = 0.f;
  for (int h = threadIdx.x; h < 512; h += 256) {
    float wgt = src[h] * g[h];
    dst[h] = f2bf(wgt);
    u += wgt; v += src[h] * bb[h];
  }
#pragma unroll
  for (int off = 32; off > 0; off >>= 1) {
    u += __shfl_xor(u, off);
    v += __shfl_xor(v, off);
  }
  __shared__ float red[8];
  const int lane = threadIdx.x & 63, wv = threadIdx.x >> 6;
  if (lane == 0) { red[wv] = u; red[4 + wv] = v; }
  __syncthreads();
  if (threadIdx.x == 0) {
    Ucb[row] = red[0] + red[1] + red[2] + red[3];
    Vcb[row] = red[4] + red[5] + red[6] + red[7];
  }
}

// both heads' prelu+cvt in one launch
__global__ __launch_bounds__(256) void prelu2(const float* __restrict__ S0,
                                              const float* __restrict__ S1,
                                              unsigned short* __restrict__ D,
                                              const float* __restrict__ a0p,
                                              const float* __restrict__ a1p, int n) {
  const float a0 = a0p[0], a1 = a1p[0];
  for (int i = blockIdx.x * 256 + threadIdx.x; i < 2 * n; i += gridDim.x * 256) {
    float v = (i < n) ? S0[i] : S1[i - n];
    float a = (i < n) ? a0 : a1;
    v = v >= 0.f ? v : a * v;
    D[i] = f2bf(v);
  }
}

// ---------------- input transpose + GN affine + bf16 -----------------------
__global__ __launch_bounds__(256) void tin(const float* __restrict__ X,
                                           unsigned short* __restrict__ Xt,
                                           const float* __restrict__ g,
                                           const float* __restrict__ bt,
                                           const float* __restrict__ sIn, float invN) {
  const int b = blockIdx.z, c0 = blockIdx.y * 64, t0 = blockIdx.x * 64;
  __shared__ float tile[64][65];
  const int tid = threadIdx.x;
  const float mean = sIn[b * 2] * invN;
  const float rs = rsqrtf(sIn[b * 2 + 1] * invN - mean * mean + 1e-8f);
  {
    const int cl = tid >> 2, tq = (tid & 3) * 16;
    const float* Xr = X + ((size_t)b * 256 + c0 + cl) * T_;
#pragma unroll
    for (int j = 0; j < 4; ++j) {
      int tt = t0 + tq + j * 4;
      float4 v;
      if (tt + 3 < T_) v = *(const float4*)(Xr + tt);
      else {
        v.x = (tt + 0 < T_) ? Xr[tt + 0] : 0.f;
        v.y = (tt + 1 < T_) ? Xr[tt + 1] : 0.f;
        v.z = (tt + 2 < T_) ? Xr[tt + 2] : 0.f;
        v.w = (tt + 3 < T_) ? Xr[tt + 3] : 0.f;
      }
      tile[cl][tq + j * 4 + 0] = v.x; tile[cl][tq + j * 4 + 1] = v.y;
      tile[cl][tq + j * 4 + 2] = v.z; tile[cl][tq + j * 4 + 3] = v.w;
    }
  }
  __syncthreads();
  {
    const int tl = tid >> 2, cq = (tid & 3) * 16;
    const int t = t0 + tl;
    if (t < T_) {
      unsigned short* dst = Xt + ((size_t)b * TP_ + t) * 256 + c0 + cq;
      s8v u0, u1;
#pragma unroll
      for (int j = 0; j < 16; ++j) {
        int c = c0 + cq + j;
        float sc = rs * g[c];
        float oc = bt[c] - mean * sc;
        unsigned short uu = f2bf(tile[cq + j][tl] * sc + oc);
        if (j < 8) u0[j] = (short)uu; else u1[j - 8] = (short)uu;
      }
      *(s8v*)dst = u0;
      *(s8v*)(dst + 8) = u1;
    }
  }
}

// ---------------- mm6 params ------------------------------------------------
struct MMP {
  const unsigned short *A0, *A1, *B0, *B1;
  const float *bias0, *bias1;
  float *O0a, *O0b, *O1a, *O1b;
  unsigned short *Obf0, *Obf1;
  const float *al0, *al1;
  float *so0, *so1;
  const float *si0, *si1;
  const float *Uc0, *Uc1, *Vc0, *Vc1, *rb0, *rb1, *sb0, *sb1;
  float* feat;
  float* dupO0; unsigned short* dupObf; float* dupO1;
  int K; float invN;
};

// ---------------- clean bf16 MFMA GEMM, 128m x TNt x 64k -------------------
// EPI 0: O0 fp32 [t][128] = v+bias, Obf shadow                (bn1)
// EPI 1: prelu -> Obf bf16 [t][512] + masked GN stats          (pw)
// EPI 2: GN2-folded; y==0: res RMW O0 + shadow; y==1: skip RMW O1
//        WF: also write feat [128][4000]; DUP: also write fork copies
// EPI 3: masked fp32 scatter O0[b][256][4000] = v+bias         (heads)
// FLG: 1=PAIR (blockIdx.z >= gridDim.z/2 -> branch-2 pointers)
template <int EPI, int TN, int FLG>
__global__ __launch_bounds__(256) void mm6(MMP p) {
  constexpr bool PAIR = (FLG & 1) != 0;
  constexpr bool WF   = (FLG & 2) != 0;
  constexpr bool DUPF = (FLG & 4) != 0;
  constexpr int NJ = TN / 32;
  __shared__ unsigned short As[128 * 64];
  __shared__ unsigned short Bs[TN * 64];
  __shared__ float redw[8];
  int b = blockIdx.z; bool br2 = false;
  if constexpr (PAIR) {
    const int h = gridDim.z >> 1;
    if (b >= h) { br2 = true; b -= h; }
  }
  const int K = p.K;
  const unsigned short* A  = br2 ? p.A1 : p.A0;
  const unsigned short* Bm = br2 ? p.B1 : p.B0;
  const int m0 = blockIdx.y * 128;
  const int t0 = blockIdx.x * TN;
  const int tid = threadIdx.x;
  const int lane = tid & 63;
  const int w = tid >> 6;
  const int wm = w >> 1, wn = w & 1;
  const int lt = lane & 15, lg = lane >> 4;
  const unsigned short* Ab = A + (size_t)m0 * K;
  const unsigned short* Bb = Bm + ((size_t)b * TP_ + t0) * K;
  const int srow8 = lane >> 3;
  const int skc   = ((lane & 7) ^ (lane >> 3)) * 8;

  f32x4 acc[4][NJ];
#pragma unroll
  for (int i = 0; i < 4; ++i)
#pragma unroll
    for (int j = 0; j < NJ; ++j) acc[i][j] = (f32x4){0.f, 0.f, 0.f, 0.f};

  for (int k0 = 0; k0 < K; k0 += 64) {
#pragma unroll
    for (int c = 0; c < 4; ++c) {
      const int ch = w * 4 + c;
      g2lds16(Ab + (size_t)(ch * 8 + srow8) * K + k0 + skc, &As[ch * 512]);
    }
#pragma unroll
    for (int c = 0; c < NJ; ++c) {
      const int ch = w * NJ + c;
      g2lds16(Bb + (size_t)(ch * 8 + srow8) * K + k0 + skc, &Bs[ch * 512]);
    }
    __syncthreads();
#pragma unroll
    for (int ks = 0; ks < 2; ++ks) {
      s8v bfr[NJ];
#pragma unroll
      for (int j = 0; j < NJ; ++j) {
        const int R = wn * (TN / 2) + j * 16 + lt;
        bfr[j] = *(const s8v*)&Bs[R * 64 + (((ks * 4 + lg) ^ (R & 7)) * 8)];
      }
#pragma unroll
      for (int i = 0; i < 4; ++i) {
        const int R = wm * 64 + i * 16 + lt;
        s8v af = *(const s8v*)&As[R * 64 + (((ks * 4 + lg) ^ (R & 7)) * 8)];
#pragma unroll
        for (int j = 0; j < NJ; ++j)
          acc[i][j] = __builtin_amdgcn_mfma_f32_16x16x32_bf16(af, bfr[j], acc[i][j], 0, 0, 0);
      }
    }
    __syncthreads();
  }

  // ---- epilogues. D row m = m0 + wm*64 + i*16 + lg*4 + r,
  //                 D col t = t0 + wn*(TN/2) + j*16 + lt
  if constexpr (EPI == 0) {
    const float* bias = p.bias0;
#pragma unroll
    for (int i = 0; i < 4; ++i) {
      const int mg = m0 + wm * 64 + i * 16 + lg * 4;
      float4 bi = *(const float4*)(bias + mg);
#pragma unroll
      for (int j = 0; j < NJ; ++j) {
        const int t = t0 + wn * (TN / 2) + j * 16 + lt;
        f32x4 v = acc[i][j];
        float nv[4] = {v[0] + bi.x, v[1] + bi.y, v[2] + bi.z, v[3] + bi.w};
        *(float4*)(p.O0a + ((size_t)b * TP_ + t) * 128 + mg) =
            make_float4(nv[0], nv[1], nv[2], nv[3]);
        u16x4 pk;
#pragma unroll
        for (int r = 0; r < 4; ++r) pk[r] = f2bf(nv[r]);
        *(u16x4*)(p.Obf0 + ((size_t)b * TP_ + t) * 128 + mg) = pk;
      }
    }
  } else if constexpr (EPI == 1) {
    const float* bias = br2 ? p.bias1 : p.bias0;
    unsigned short* Obf = br2 ? p.Obf1 : p.Obf0;
    const float aO = (br2 ? p.al1 : p.al0)[0];
    float* so = br2 ? p.so1 : p.so0;
    float s1 = 0.f, s2 = 0.f;
#pragma unroll
    for (int i = 0; i < 4; ++i) {
      const int mg = m0 + wm * 64 + i * 16 + lg * 4;
      float4 bi = *(const float4*)(bias + mg);
      float bv[4] = {bi.x, bi.y, bi.z, bi.w};
#pragma unroll
      for (int j = 0; j < NJ; ++j) {
        const int t = t0 + wn * (TN / 2) + j * 16 + lt;
        f32x4 v = acc[i][j];
        u16x4 pk;
#pragma unroll
        for (int r = 0; r < 4; ++r) {
          float f = v[r] + bv[r];
          f = f >= 0.f ? f : aO * f;
          pk[r] = f2bf(f);
        }
        *(u16x4*)(Obf + ((size_t)b * TP_ + t) * 512 + mg) = pk;
        if (t < T_) {
#pragma unroll
          for (int r = 0; r < 4; ++r) { float f = bf2f(pk[r]); s1 += f; s2 += f * f; }
        }
      }
    }
#pragma unroll
    for (int off = 32; off > 0; off >>= 1) {
      s1 += __shfl_xor(s1, off);
      s2 += __shfl_xor(s2, off);
    }
    if (lane == 0) { redw[w] = s1; redw[4 + w] = s2; }
    __syncthreads();
    if (tid == 0) {
      atomicAdd(&so[b * 2 + 0], redw[0] + redw[1] + redw[2] + redw[3]);
      atomicAdd(&so[b * 2 + 1], redw[4] + redw[5] + redw[6] + redw[7]);
    }
  } else if constexpr (EPI == 2) {
    float* O0 = br2 ? p.O0b : p.O0a;
    float* O1 = br2 ? p.O1b : p.O1a;
    unsigned short* Obf = br2 ? p.Obf1 : p.Obf0;
    const float* si = br2 ? p.si1 : p.si0;
    const float* Uc = br2 ? p.Uc1 : p.Uc0;
    const float* Vc = br2 ? p.Vc1 : p.Vc0;
    const float* rb = br2 ? p.rb1 : p.rb0;
    const float* sb = br2 ? p.sb1 : p.sb0;
    const float mean = si[b * 2] * p.invN;
    const float rsv = rsqrtf(si[b * 2 + 1] * p.invN - mean * mean + 1e-8f);
    const bool isRes = (m0 == 0);
#pragma unroll
    for (int i = 0; i < 4; ++i) {
      const int ml = wm * 64 + i * 16 + lg * 4;   // 0..127 local
      float cc[4];
#pragma unroll
      for (int r = 0; r < 4; ++r) {
        const int mgG = m0 + ml + r;
        cc[r] = Vc[mgG] - mean * rsv * Uc[mgG] + (isRes ? rb[ml + r] : sb[ml + r]);
      }
#pragma unroll
      for (int j = 0; j < NJ; ++j) {
        const int t = t0 + wn * (TN / 2) + j * 16 + lt;
        f32x4 v = acc[i][j];
        if (isRes) {
          float* ptr = O0 + ((size_t)b * TP_ + t) * 128 + ml;
          float4 old = *(float4*)ptr;
          float nv[4] = {old.x + rsv * v[0] + cc[0], old.y + rsv * v[1] + cc[1],
                         old.z + rsv * v[2] + cc[2], old.w + rsv * v[3] + cc[3]};
          *(float4*)ptr = make_float4(nv[0], nv[1], nv[2], nv[3]);
          u16x4 pk;
#pragma unroll
          for (int r = 0; r < 4; ++r) pk[r] = f2bf(nv[r]);
          *(u16x4*)(Obf + ((size_t)b * TP_ + t) * 128 + ml) = pk;
          if constexpr (DUPF) {
            *(float4*)(p.dupO0 + ((size_t)b * TP_ + t) * 128 + ml) =
                make_float4(nv[0], nv[1], nv[2], nv[3]);
            *(u16x4*)(p.dupObf + ((size_t)b * TP_ + t) * 128 + ml) = pk;
          }
          if constexpr (WF) {
            if (t < T_) {
#pragma unroll
              for (int r = 0; r < 4; ++r)
                p.feat[((size_t)b * 128 + ml + r) * T_ + t] = nv[r];
            }
          }
        } else {
          float* ptr = O1 + ((size_t)b * TP_ + t) * 128 + ml;
          float4 old = *(float4*)ptr;
          float nv[4] = {old.x + rsv * v[0] + cc[0], old.y + rsv * v[1] + cc[1],
                         old.z + rsv * v[2] + cc[2], old.w + rsv * v[3] + cc[3]};
          *(float4*)ptr = make_float4(nv[0], nv[1], nv[2], nv[3]);
          if constexpr (DUPF) {
            *(float4*)(p.dupO1 + ((size_t)b * TP_ + t) * 128 + ml) =
                make_float4(nv[0], nv[1], nv[2], nv[3]);
          }
        }
      }
    }
  } else {  // EPI 3: heads scatter to [b][256][4000]
    float* O0 = br2 ? p.O0b : p.O0a;
    const float* bias = br2 ? p.bias1 : p.bias0;
#pragma unroll
    for (int i = 0; i < 4; ++i) {
      const int mg = m0 + wm * 64 + i * 16 + lg * 4;
#pragma unroll
      for (int j = 0; j < NJ; ++j) {
        const int t = t0 + wn * (TN / 2) + j * 16 + lt;
        if (t < T_) {
          f32x4 v = acc[i][j];
#pragma unroll
          for (int r = 0; r < 4; ++r)
            O0[((size_t)b * 256 + mg + r) * T_ + t] = v[r] + bias[mg + r];
        }
      }
    }
  }
}

// ---------------- depthwise dilated conv, [t][h], branch-pair capable ------
__global__ __launch_bounds__(256) void dw3(
    const unsigned short* __restrict__ Y, unsigned short* __restrict__ U,
    const float* __restrict__ dww0, const float* __restrict__ dww1,
    const float* __restrict__ dwb0, const float* __restrict__ dwb1,
    const float* __restrict__ g10, const float* __restrict__ g11,
    const float* __restrict__ b10, const float* __restrict__ b11,
    const float* __restrict__ p20, const float* __restrict__ p21,
    const float* __restrict__ sIn0, const float* __restrict__ sIn1, float invN,
    float* __restrict__ sOut0, float* __restrict__ sOut1, int dil, int halfY) {
  const int q = blockIdx.y;
  const bool br2 = q >= halfY;
  const int b = br2 ? q - halfY : q;
  const float* dww = br2 ? dww1 : dww0;
  const float* dwb = br2 ? dwb1 : dwb0;
  const float* g1  = br2 ? g11 : g10;
  const float* b1  = br2 ? b11 : b10;
  const float* p2p = br2 ? p21 : p20;
  const float* sIn = br2 ? sIn1 : sIn0;
  float* sOut      = br2 ? sOut1 : sOut0;
  const int tid = threadIdx.x;
  const int hc = (tid & 63) * 8;
  const int tbase = blockIdx.x * 16 + (tid >> 6) * 4;

  const float mean = sIn[b * 2] * invN;
  const float rs = rsqrtf(sIn[b * 2 + 1] * invN - mean * mean + 1e-8f);
  float sA[8], oA[8], w0[8], w1[8], w2[8], bb[8];
#pragma unroll
  for (int j = 0; j < 8; ++j) {
    sA[j] = rs * g1[hc + j];
    oA[j] = b1[hc + j] - mean * sA[j];
    w0[j] = dww[(hc + j) * 3 + 0];
    w1[j] = dww[(hc + j) * 3 + 1];
    w2[j] = dww[(hc + j) * 3 + 2];
    bb[j] = dwb[hc + j];
  }
  const float alpha = p2p[0];
  const unsigned short* Yb = Y + (size_t)q * TP_ * 512;
  unsigned short* Ub = U + (size_t)q * TP_ * 512;
  float s1 = 0.f, s2 = 0.f;
#pragma unroll
  for (int i = 0; i < 4; ++i) {
    const int t = tbase + i;
    const int tm = t - dil, tp = t + dil;
    const bool vm = (tm >= 0), vp = (tp < T_);
    s8v xm = {0, 0, 0, 0, 0, 0, 0, 0};
    s8v xp = {0, 0, 0, 0, 0, 0, 0, 0};
    s8v x0 = *(const s8v*)(Yb + (size_t)t * 512 + hc);
    if (vm) xm = *(const s8v*)(Yb + (size_t)tm * 512 + hc);
    if (vp) xp = *(const s8v*)(Yb + (size_t)tp * 512 + hc);
    s8v out;
#pragma unroll
    for (int j = 0; j < 8; ++j) {
      float fm = vm ? (bf2f((unsigned short)xm[j]) * sA[j] + oA[j]) : 0.f;
      float f0 = bf2f((unsigned short)x0[j]) * sA[j] + oA[j];
      float fp = vp ? (bf2f((unsigned short)xp[j]) * sA[j] + oA[j]) : 0.f;
      float v = fmaf(w0[j], fm, fmaf(w1[j], f0, fmaf(w2[j], fp, bb[j])));
      v = v >= 0.f ? v : alpha * v;
      unsigned short u = f2bf(v);
      out[j] = (short)u;
      float f = bf2f(u);
      s1 += f; s2 += f * f;
    }
    *(s8v*)(Ub + (size_t)t * 512 + hc) = out;
  }
#pragma unroll
  for (int off = 32; off > 0; off >>= 1) {
    s1 += __shfl_xor(s1, off);
    s2 += __shfl_xor(s2, off);
  }
  __shared__ float red[8];
  const int lane = tid & 63, wv = tid >> 6;
  if (lane == 0) { red[wv] = s1; red[4 + wv] = s2; }
  __syncthreads();
  if (tid == 0) {
    atomicAdd(&sOut[b * 2 + 0], red[0] + red[1] + red[2] + red[3]);
    atomicAdd(&sOut[b * 2 + 1], red[4] + red[5] + red[6] + red[7]);
  }
}

// ---------------------------------------------------------------------------
extern "C" void kernel_launch(void* const* d_in, const int* in_sizes, int n_in,
                              void* d_out, int out_size, void* d_ws, size_t ws_size,
                              hipStream_t stream) {
  (void)in_sizes; (void)n_in; (void)out_size; (void)ws_size;
  const float* input = (const float*)d_in[0];
  const float* ln1_g = (const float*)d_in[1];
  const float* ln1_b = (const float*)d_in[2];
  const float* bn1_w = (const float*)d_in[3];
  const float* bn1_b = (const float*)d_in[4];
  const float* pw_w  = (const float*)d_in[5];
  const float* pw_b  = (const float*)d_in[6];
  const float* dw_w  = (const float*)d_in[7];
  const float* dw_b  = (const float*)d_in[8];
  const float* res_w = (const float*)d_in[9];
  const float* res_b = (const float*)d_in[10];
  const float* sk_w  = (const float*)d_in[11];
  const float* sk_b  = (const float*)d_in[12];
  const float* p1    = (const float*)d_in[13];
  const float* p2    = (const float*)d_in[14];
  const float* n1g   = (const float*)d_in[15];
  const float* n1b   = (const float*)d_in[16];
  const float* n2g   = (const float*)d_in[17];
  const float* n2b   = (const float*)d_in[18];
  const float* h1_p  = (const float*)d_in[19];
  const float* h1_w  = (const float*)d_in[20];
  const float* h1_b  = (const float*)d_in[21];
  const float* h2_p  = (const float*)d_in[22];
  const float* h2_w  = (const float*)d_in[23];
  const float* h2_b  = (const float*)d_in[24];

  float* out1 = (float*)d_out;
  float* out2 = out1 + 4096000;   // [4,256,4000]
  float* feat = out1 + 8192000;   // [4,128,4000]

  char* base = (char*)d_ws;
  float* OUTS  = (float*)base;                  base += (size_t)B_ * TP_ * 128 * 4;
  float* SKIP  = (float*)base;                  base += (size_t)B_ * TP_ * 128 * 4;
  float* OUT2  = (float*)base;                  base += (size_t)B_ * TP_ * 128 * 4;
  float* SKIP2 = (float*)base;                  base += (size_t)B_ * TP_ * 128 * 4;
  unsigned short* OUTbf  = (unsigned short*)base; base += (size_t)B_ * TP_ * 128 * 2;
  unsigned short* OUT2bf = (unsigned short*)base; base += (size_t)B_ * TP_ * 128 * 2;
  unsigned short* Ybuf = (unsigned short*)base; base += (size_t)8 * TP_ * 512 * 2;  // 8 slots
  unsigned short* Ubuf = (unsigned short*)base; base += (size_t)8 * TP_ * 512 * 2;  // 8 slots
  unsigned short* Xt   = (unsigned short*)base; base += (size_t)B_ * TP_ * 256 * 2;
  unsigned short* SKbf = (unsigned short*)base; base += (size_t)2 * B_ * TP_ * 128 * 2;
  unsigned short* Wpw  = (unsigned short*)base; base += (size_t)32 * 512 * 128 * 2;
  unsigned short* Wg   = (unsigned short*)base; base += (size_t)32 * 256 * 512 * 2;
  unsigned short* Wbn  = (unsigned short*)base; base += (size_t)128 * 256 * 2;
  unsigned short* Wh1  = (unsigned short*)base; base += (size_t)256 * 128 * 2;
  unsigned short* Wh2  = (unsigned short*)base; base += (size_t)256 * 128 * 2;
  float* UVu   = (float*)base;                  base += (size_t)32 * 256 * 4;
  float* UVv   = (float*)base;                  base += (size_t)32 * 256 * 4;
  float* STATS = (float*)base;

  const size_t YSL = (size_t)TP_ * 512;       // per-slot Y/U stride (elements)
  const int npr = B_ * TP_ * 128;

  hipMemsetAsync(STATS, 0, 65 * 8 * sizeof(float), stream);
  hipMemsetAsync(SKIP, 0, (size_t)B_ * TP_ * 128 * sizeof(float), stream);

  const float invN_in = 1.0f / (256.0f * 4000.0f);
  const float invN_h  = 1.0f / (512.0f * 4000.0f);

  // weight prep
  cvt_bf<<<2048, 256, 0, stream>>>(pw_w, Wpw, 32 * 512 * 128);
  cvt_bf<<<128, 256, 0, stream>>>(bn1_w, Wbn, 128 * 256);
  cvt_bf<<<128, 256, 0, stream>>>(h1_w, Wh1, 256 * 128);
  cvt_bf<<<128, 256, 0, stream>>>(h2_w, Wh2, 256 * 128);
  fold_rs<<<32 * 256, 256, 0, stream>>>(res_w, sk_w, n2g, n2b, Wg, UVu, UVv);

  // input GN -> bf16 [t][256] -> bottleneck GEMM
  gn_stats<<<dim3(64, B_), 256, 0, stream>>>(input, STATS, 256 * T_);
  tin<<<dim3(63, 4, B_), 256, 0, stream>>>(input, Xt, ln1_g, ln1_b, STATS, invN_in);
  {
    MMP q{}; q.A0 = Wbn; q.B0 = Xt; q.bias0 = bn1_b; q.O0a = OUTS; q.Obf0 = OUTbf;
    q.K = 256;
    mm6<0, 128, 0><<<dim3(32, 1, B_), 256, 0, stream>>>(q);
  }

  // ---- serial blocks 0..15 (shared trunk)
  auto pw_one = [&](int i) {
    MMP q{}; q.A0 = Wpw + (size_t)i * 512 * 128; q.B0 = OUTbf;
    q.bias0 = pw_b + (size_t)i * 512; q.Obf0 = Ybuf; q.al0 = p1 + i;
    q.so0 = STATS + (size_t)(1 + 2 * i) * 8; q.K = 128;
    mm6<1, 128, 0><<<dim3(32, 4, B_), 256, 0, stream>>>(q);
  };
  auto dw_one = [&](int i) {
    float* sA = STATS + (size_t)(1 + 2 * i) * 8;
    float* sB = STATS + (size_t)(2 + 2 * i) * 8;
    dw3<<<dim3(250, B_), 256, 0, stream>>>(
        Ybuf, Ubuf, dw_w + (size_t)i * 512 * 3, nullptr,
        dw_b + (size_t)i * 512, nullptr, n1g + (size_t)i * 512, nullptr,
        n1b + (size_t)i * 512, nullptr, p2 + i, nullptr, sA, nullptr, invN_h,
        sB, nullptr, 1 << (i & 7), 99);
  };
  auto rs_one = [&](int i, int flg) {
    MMP q{}; q.A0 = Wg + (size_t)i * 256 * 512; q.B0 = Ubuf;
    q.O0a = OUTS; q.O1a = SKIP; q.Obf0 = OUTbf;
    q.si0 = STATS + (size_t)(2 + 2 * i) * 8; q.invN = invN_h;
    q.Uc0 = UVu + (size_t)i * 256; q.Vc0 = UVv + (size_t)i * 256;
    q.rb0 = res_b + (size_t)i * 128; q.sb0 = sk_b + (size_t)i * 128;
    q.feat = feat; q.dupO0 = OUT2; q.dupObf = OUT2bf; q.dupO1 = SKIP2;
    q.K = 512;
    if (flg == 2)      mm6<2, 64, 2><<<dim3(64, 2, B_), 256, 0, stream>>>(q);
    else if (flg == 4) mm6<2, 64, 4><<<dim3(64, 2, B_), 256, 0, stream>>>(q);
    else               mm6<2, 64, 0><<<dim3(64, 2, B_), 256, 0, stream>>>(q);
  };

  for (int i = 0; i < 16; ++i) {
    pw_one(i);
    dw_one(i);
    rs_one(i, (i == 7) ? 2 : (i == 15) ? 4 : 0);
  }

  // ---- paired blocks: branch1 = 16+j, branch2 = 24+j
  for (int j = 0; j < 8; ++j) {
    const int i1 = 16 + j, i2 = 24 + j;
    float* sA1 = STATS + (size_t)(1 + 2 * i1) * 8;
    float* sB1 = STATS + (size_t)(2 + 2 * i1) * 8;
    float* sA2 = STATS + (size_t)(1 + 2 * i2) * 8;
    float* sB2 = STATS + (size_t)(2 + 2 * i2) * 8;
    {
      MMP q{};
      q.A0 = Wpw + (size_t)i1 * 512 * 128; q.A1 = Wpw + (size_t)i2 * 512 * 128;
      q.B0 = OUTbf; q.B1 = OUT2bf;
      q.bias0 = pw_b + (size_t)i1 * 512; q.bias1 = pw_b + (size_t)i2 * 512;
      q.Obf0 = Ybuf; q.Obf1 = Ybuf + 4 * YSL;
      q.al0 = p1 + i1; q.al1 = p1 + i2;
      q.so0 = sA1; q.so1 = sA2; q.K = 128;
      mm6<1, 128, 1><<<dim3(32, 4, 2 * B_), 256, 0, stream>>>(q);
    }
    dw3<<<dim3(250, 2 * B_), 256, 0, stream>>>(
        Ybuf, Ubuf,
        dw_w + (size_t)i1 * 512 * 3, dw_w + (size_t)i2 * 512 * 3,
        dw_b + (size_t)i1 * 512, dw_b + (size_t)i2 * 512,
        n1g + (size_t)i1 * 512, n1g + (size_t)i2 * 512,
        n1b + (size_t)i1 * 512, n1b + (size_t)i2 * 512,
        p2 + i1, p2 + i2, sA1, sA2, invN_h, sB1, sB2, 1 << (j & 7), B_);
    {
      MMP q{};
      q.A0 = Wg + (size_t)i1 * 256 * 512; q.A1 = Wg + (size_t)i2 * 256 * 512;
      q.B0 = Ubuf; q.B1 = Ubuf + 4 * YSL;
      q.O0a = OUTS; q.O0b = OUT2; q.O1a = SKIP; q.O1b = SKIP2;
      q.Obf0 = OUTbf; q.Obf1 = OUT2bf;
      q.si0 = sB1; q.si1 = sB2; q.invN = invN_h;
      q.Uc0 = UVu + (size_t)i1 * 256; q.Uc1 = UVu + (size_t)i2 * 256;
      q.Vc0 = UVv + (size_t)i1 * 256; q.Vc1 = UVv + (size_t)i2 * 256;
      q.rb0 = res_b + (size_t)i1 * 128; q.rb1 = res_b + (size_t)i2 * 128;
      q.sb0 = sk_b + (size_t)i1 * 128; q.sb1 = sk_b + (size_t)i2 * 128;
      q.K = 512;
      mm6<2, 64, 1><<<dim3(64, 2, 2 * B_), 256, 0, stream>>>(q);
    }
  }

  // ---- heads (both in one pass)
  prelu2<<<2048, 256, 0, stream>>>(SKIP, SKIP2, SKbf, h1_p, h2_p, npr);
  {
    MMP q{};
    q.A0 = Wh1; q.A1 = Wh2;
    q.B0 = SKbf; q.B1 = SKbf + npr;
    q.bias0 = h1_b; q.bias1 = h2_b;
    q.O0a = out1; q.O0b = out2; q.K = 128;
    mm6<3, 128, 1><<<dim3(32, 2, 2 * B_), 256, 0, stream>>>(q);
  }
}

// Round 7
// 2122.833 us; speedup vs baseline: 2.8942x; 1.0087x over previous
//
#include <hip/hip_runtime.h>
#include <hip/hip_bf16.h>

// ---------------------------------------------------------------------------
// Conv-TasNet TCN, bf16-MFMA v6.
// vs v5: (1) dw3 loads all 12 taps UNCONDITIONALLY (Y has a 128-row halo per
// slot; OOB contribution removed by VALU select, not branch) -> MLP 1 -> 12.
// (2) paired res/skip GEMM uses TN=128 (same blocks/CU, half A-panel refetch).
// ---------------------------------------------------------------------------

#define T_  4000
#define TP_ 4096
#define B_  4
#define YHAL 128
#define YROW 512
// Y slot stride (elements) including front+back halo
#define YSST ((size_t)(TP_ + 2 * YHAL) * YROW)
// U slot stride (no halo)
#define USST ((size_t)TP_ * YROW)

typedef __attribute__((ext_vector_type(8))) short  s8v;
typedef __attribute__((ext_vector_type(4))) float  f32x4;
typedef __attribute__((ext_vector_type(4))) unsigned short u16x4;

__device__ __forceinline__ float bf2f(unsigned short u) {
  unsigned int i = ((unsigned int)u) << 16;
  float f; __builtin_memcpy(&f, &i, 4); return f;
}
__device__ __forceinline__ unsigned short f2bf(float f) {
  unsigned int i; __builtin_memcpy(&i, &f, 4);
  unsigned int r = i + 0x7fffu + ((i >> 16) & 1u);
  return (unsigned short)(r >> 16);
}

__device__ __forceinline__ void g2lds16(const void* g, void* l) {
  __builtin_amdgcn_global_load_lds(
      (const __attribute__((address_space(1))) unsigned int*)g,
      (__attribute__((address_space(3))) unsigned int*)l, 16, 0, 0);
}

// ---------------- per-sample sum/sumsq over contiguous [C*T] ---------------
__global__ __launch_bounds__(256) void gn_stats(const float* __restrict__ X,
                                                float* __restrict__ statsOut, int n) {
  const int b = blockIdx.y;
  const float4* xp = (const float4*)(X + (size_t)b * n);
  const int n4 = n >> 2;
  float s1 = 0.f, s2 = 0.f;
  for (int idx = blockIdx.x * 256 + threadIdx.x; idx < n4; idx += gridDim.x * 256) {
    float4 v = xp[idx];
    s1 += v.x + v.y + v.z + v.w;
    s2 += v.x * v.x + v.y * v.y + v.z * v.z + v.w * v.w;
  }
#pragma unroll
  for (int off = 32; off > 0; off >>= 1) {
    s1 += __shfl_xor(s1, off);
    s2 += __shfl_xor(s2, off);
  }
  __shared__ float red[8];
  const int lane = threadIdx.x & 63, wv = threadIdx.x >> 6;
  if (lane == 0) { red[wv] = s1; red[4 + wv] = s2; }
  __syncthreads();
  if (threadIdx.x == 0) {
    atomicAdd(&statsOut[b * 2 + 0], red[0] + red[1] + red[2] + red[3]);
    atomicAdd(&statsOut[b * 2 + 1], red[4] + red[5] + red[6] + red[7]);
  }
}

// ---------------- weight prep ----------------------------------------------
__global__ __launch_bounds__(256) void cvt_bf(const float* __restrict__ s,
                                              unsigned short* __restrict__ d, int n) {
  for (int i = blockIdx.x * 256 + threadIdx.x; i < n; i += gridDim.x * 256)
    d[i] = f2bf(s[i]);
}

__global__ __launch_bounds__(256) void fold_rs(
    const float* __restrict__ rw, const float* __restrict__ sw,
    const float* __restrict__ g2a, const float* __restrict__ b2a,
    unsigned short* __restrict__ Wg, float* __restrict__ Ucb,
    float* __restrict__ Vcb) {
  const int row = blockIdx.x;                 // i*256 + m
  const int i = row >> 8, m = row & 255;
  const float* src = (m < 128) ? rw + ((size_t)i * 128 + m) * 512
                               : sw + ((size_t)i * 128 + (m - 128)) * 512;
  const float* g = g2a + (size_t)i * 512;
  const float* bb = b2a + (size_t)i * 512;
  unsigned short* dst = Wg + (size_t)row * 512;
  float u = 0.f, v = 0.f;
  for (int h = threadIdx.x; h < 512; h += 256) {
    float wgt = src[h] * g[h];
    dst[h] = f2bf(wgt);
    u += wgt; v += src[h] * bb[h];
  }
#pragma unroll
  for (int off = 32; off > 0; off >>= 1) {
    u += __shfl_xor(u, off);
    v += __shfl_xor(v, off);
  }
  __shared__ float red[8];
  const int lane = threadIdx.x & 63, wv = threadIdx.x >> 6;
  if (lane == 0) { red[wv] = u; red[4 + wv] = v; }
  __syncthreads();
  if (threadIdx.x == 0) {
    Ucb[row] = red[0] + red[1] + red[2] + red[3];
    Vcb[row] = red[4] + red[5] + red[6] + red[7];
  }
}

// both heads' prelu+cvt in one launch
__global__ __launch_bounds__(256) void prelu2(const float* __restrict__ S0,
                                              const float* __restrict__ S1,
                                              unsigned short* __restrict__ D,
                                              const float* __restrict__ a0p,
                                              const float* __restrict__ a1p, int n) {
  const float a0 = a0p[0], a1 = a1p[0];
  for (int i = blockIdx.x * 256 + threadIdx.x; i < 2 * n; i += gridDim.x * 256) {
    float v = (i < n) ? S0[i] : S1[i - n];
    float a = (i < n) ? a0 : a1;
    v = v >= 0.f ? v : a * v;
    D[i] = f2bf(v);
  }
}

// ---------------- input transpose + GN affine + bf16 -----------------------
__global__ __launch_bounds__(256) void tin(const float* __restrict__ X,
                                           unsigned short* __restrict__ Xt,
                                           const float* __restrict__ g,
                                           const float* __restrict__ bt,
                                           const float* __restrict__ sIn, float invN) {
  const int b = blockIdx.z, c0 = blockIdx.y * 64, t0 = blockIdx.x * 64;
  __shared__ float tile[64][65];
  const int tid = threadIdx.x;
  const float mean = sIn[b * 2] * invN;
  const float rs = rsqrtf(sIn[b * 2 + 1] * invN - mean * mean + 1e-8f);
  {
    const int cl = tid >> 2, tq = (tid & 3) * 16;
    const float* Xr = X + ((size_t)b * 256 + c0 + cl) * T_;
#pragma unroll
    for (int j = 0; j < 4; ++j) {
      int tt = t0 + tq + j * 4;
      float4 v;
      if (tt + 3 < T_) v = *(const float4*)(Xr + tt);
      else {
        v.x = (tt + 0 < T_) ? Xr[tt + 0] : 0.f;
        v.y = (tt + 1 < T_) ? Xr[tt + 1] : 0.f;
        v.z = (tt + 2 < T_) ? Xr[tt + 2] : 0.f;
        v.w = (tt + 3 < T_) ? Xr[tt + 3] : 0.f;
      }
      tile[cl][tq + j * 4 + 0] = v.x; tile[cl][tq + j * 4 + 1] = v.y;
      tile[cl][tq + j * 4 + 2] = v.z; tile[cl][tq + j * 4 + 3] = v.w;
    }
  }
  __syncthreads();
  {
    const int tl = tid >> 2, cq = (tid & 3) * 16;
    const int t = t0 + tl;
    if (t < T_) {
      unsigned short* dst = Xt + ((size_t)b * TP_ + t) * 256 + c0 + cq;
      s8v u0, u1;
#pragma unroll
      for (int j = 0; j < 16; ++j) {
        int c = c0 + cq + j;
        float sc = rs * g[c];
        float oc = bt[c] - mean * sc;
        unsigned short uu = f2bf(tile[cq + j][tl] * sc + oc);
        if (j < 8) u0[j] = (short)uu; else u1[j - 8] = (short)uu;
      }
      *(s8v*)dst = u0;
      *(s8v*)(dst + 8) = u1;
    }
  }
}

// ---------------- mm6 params ------------------------------------------------
struct MMP {
  const unsigned short *A0, *A1, *B0, *B1;
  const float *bias0, *bias1;
  float *O0a, *O0b, *O1a, *O1b;
  unsigned short *Obf0, *Obf1;
  const float *al0, *al1;
  float *so0, *so1;
  const float *si0, *si1;
  const float *Uc0, *Uc1, *Vc0, *Vc1, *rb0, *rb1, *sb0, *sb1;
  float* feat;
  float* dupO0; unsigned short* dupObf; float* dupO1;
  int K; float invN;
};

// ---------------- clean bf16 MFMA GEMM, 128m x TNt x 64k -------------------
// EPI 0: O0 fp32 [t][128] = v+bias, Obf shadow                (bn1)
// EPI 1: prelu -> Obf bf16 Y-slot (halo stride YSST) + GN stats (pw)
// EPI 2: GN2-folded; y==0: res RMW O0 + shadow; y==1: skip RMW O1
//        WF: also write feat [128][4000]; DUP: also write fork copies
// EPI 3: masked fp32 scatter O0[b][256][4000] = v+bias         (heads)
// FLG: 1=PAIR (blockIdx.z >= gridDim.z/2 -> branch-2 pointers)
template <int EPI, int TN, int FLG>
__global__ __launch_bounds__(256) void mm6(MMP p) {
  constexpr bool PAIR = (FLG & 1) != 0;
  constexpr bool WF   = (FLG & 2) != 0;
  constexpr bool DUPF = (FLG & 4) != 0;
  constexpr int NJ = TN / 32;
  __shared__ unsigned short As[128 * 64];
  __shared__ unsigned short Bs[TN * 64];
  __shared__ float redw[8];
  int b = blockIdx.z; bool br2 = false;
  if constexpr (PAIR) {
    const int h = gridDim.z >> 1;
    if (b >= h) { br2 = true; b -= h; }
  }
  const int K = p.K;
  const unsigned short* A  = br2 ? p.A1 : p.A0;
  const unsigned short* Bm = br2 ? p.B1 : p.B0;
  const int m0 = blockIdx.y * 128;
  const int t0 = blockIdx.x * TN;
  const int tid = threadIdx.x;
  const int lane = tid & 63;
  const int w = tid >> 6;
  const int wm = w >> 1, wn = w & 1;
  const int lt = lane & 15, lg = lane >> 4;
  const unsigned short* Ab = A + (size_t)m0 * K;
  const unsigned short* Bb = Bm + ((size_t)b * TP_ + t0) * K;
  const int srow8 = lane >> 3;
  const int skc   = ((lane & 7) ^ (lane >> 3)) * 8;

  f32x4 acc[4][NJ];
#pragma unroll
  for (int i = 0; i < 4; ++i)
#pragma unroll
    for (int j = 0; j < NJ; ++j) acc[i][j] = (f32x4){0.f, 0.f, 0.f, 0.f};

  for (int k0 = 0; k0 < K; k0 += 64) {
#pragma unroll
    for (int c = 0; c < 4; ++c) {
      const int ch = w * 4 + c;
      g2lds16(Ab + (size_t)(ch * 8 + srow8) * K + k0 + skc, &As[ch * 512]);
    }
#pragma unroll
    for (int c = 0; c < NJ; ++c) {
      const int ch = w * NJ + c;
      g2lds16(Bb + (size_t)(ch * 8 + srow8) * K + k0 + skc, &Bs[ch * 512]);
    }
    __syncthreads();
#pragma unroll
    for (int ks = 0; ks < 2; ++ks) {
      s8v bfr[NJ];
#pragma unroll
      for (int j = 0; j < NJ; ++j) {
        const int R = wn * (TN / 2) + j * 16 + lt;
        bfr[j] = *(const s8v*)&Bs[R * 64 + (((ks * 4 + lg) ^ (R & 7)) * 8)];
      }
#pragma unroll
      for (int i = 0; i < 4; ++i) {
        const int R = wm * 64 + i * 16 + lt;
        s8v af = *(const s8v*)&As[R * 64 + (((ks * 4 + lg) ^ (R & 7)) * 8)];
#pragma unroll
        for (int j = 0; j < NJ; ++j)
          acc[i][j] = __builtin_amdgcn_mfma_f32_16x16x32_bf16(af, bfr[j], acc[i][j], 0, 0, 0);
      }
    }
    __syncthreads();
  }

  // ---- epilogues. D row m = m0 + wm*64 + i*16 + lg*4 + r,
  //                 D col t = t0 + wn*(TN/2) + j*16 + lt
  if constexpr (EPI == 0) {
    const float* bias = p.bias0;
#pragma unroll
    for (int i = 0; i < 4; ++i) {
      const int mg = m0 + wm * 64 + i * 16 + lg * 4;
      float4 bi = *(const float4*)(bias + mg);
#pragma unroll
      for (int j = 0; j < NJ; ++j) {
        const int t = t0 + wn * (TN / 2) + j * 16 + lt;
        f32x4 v = acc[i][j];
        float nv[4] = {v[0] + bi.x, v[1] + bi.y, v[2] + bi.z, v[3] + bi.w};
        *(float4*)(p.O0a + ((size_t)b * TP_ + t) * 128 + mg) =
            make_float4(nv[0], nv[1], nv[2], nv[3]);
        u16x4 pk;
#pragma unroll
        for (int r = 0; r < 4; ++r) pk[r] = f2bf(nv[r]);
        *(u16x4*)(p.Obf0 + ((size_t)b * TP_ + t) * 128 + mg) = pk;
      }
    }
  } else if constexpr (EPI == 1) {
    // Y-slot output with halo stride
    const float* bias = br2 ? p.bias1 : p.bias0;
    unsigned short* Obf = (br2 ? p.Obf1 : p.Obf0) + (size_t)b * YSST;
    const float aO = (br2 ? p.al1 : p.al0)[0];
    float* so = br2 ? p.so1 : p.so0;
    float s1 = 0.f, s2 = 0.f;
#pragma unroll
    for (int i = 0; i < 4; ++i) {
      const int mg = m0 + wm * 64 + i * 16 + lg * 4;
      float4 bi = *(const float4*)(bias + mg);
      float bv[4] = {bi.x, bi.y, bi.z, bi.w};
#pragma unroll
      for (int j = 0; j < NJ; ++j) {
        const int t = t0 + wn * (TN / 2) + j * 16 + lt;
        f32x4 v = acc[i][j];
        u16x4 pk;
#pragma unroll
        for (int r = 0; r < 4; ++r) {
          float f = v[r] + bv[r];
          f = f >= 0.f ? f : aO * f;
          pk[r] = f2bf(f);
        }
        *(u16x4*)(Obf + (size_t)t * YROW + mg) = pk;
        if (t < T_) {
#pragma unroll
          for (int r = 0; r < 4; ++r) { float f = bf2f(pk[r]); s1 += f; s2 += f * f; }
        }
      }
    }
#pragma unroll
    for (int off = 32; off > 0; off >>= 1) {
      s1 += __shfl_xor(s1, off);
      s2 += __shfl_xor(s2, off);
    }
    if (lane == 0) { redw[w] = s1; redw[4 + w] = s2; }
    __syncthreads();
    if (tid == 0) {
      atomicAdd(&so[b * 2 + 0], redw[0] + redw[1] + redw[2] + redw[3]);
      atomicAdd(&so[b * 2 + 1], redw[4] + redw[5] + redw[6] + redw[7]);
    }
  } else if constexpr (EPI == 2) {
    float* O0 = br2 ? p.O0b : p.O0a;
    float* O1 = br2 ? p.O1b : p.O1a;
    unsigned short* Obf = br2 ? p.Obf1 : p.Obf0;
    const float* si = br2 ? p.si1 : p.si0;
    const float* Uc = br2 ? p.Uc1 : p.Uc0;
    const float* Vc = br2 ? p.Vc1 : p.Vc0;
    const float* rb = br2 ? p.rb1 : p.rb0;
    const float* sb = br2 ? p.sb1 : p.sb0;
    const float mean = si[b * 2] * p.invN;
    const float rsv = rsqrtf(si[b * 2 + 1] * p.invN - mean * mean + 1e-8f);
    const bool isRes = (m0 == 0);
#pragma unroll
    for (int i = 0; i < 4; ++i) {
      const int ml = wm * 64 + i * 16 + lg * 4;   // 0..127 local
      float cc[4];
#pragma unroll
      for (int r = 0; r < 4; ++r) {
        const int mgG = m0 + ml + r;
        cc[r] = Vc[mgG] - mean * rsv * Uc[mgG] + (isRes ? rb[ml + r] : sb[ml + r]);
      }
#pragma unroll
      for (int j = 0; j < NJ; ++j) {
        const int t = t0 + wn * (TN / 2) + j * 16 + lt;
        f32x4 v = acc[i][j];
        if (isRes) {
          float* ptr = O0 + ((size_t)b * TP_ + t) * 128 + ml;
          float4 old = *(float4*)ptr;
          float nv[4] = {old.x + rsv * v[0] + cc[0], old.y + rsv * v[1] + cc[1],
                         old.z + rsv * v[2] + cc[2], old.w + rsv * v[3] + cc[3]};
          *(float4*)ptr = make_float4(nv[0], nv[1], nv[2], nv[3]);
          u16x4 pk;
#pragma unroll
          for (int r = 0; r < 4; ++r) pk[r] = f2bf(nv[r]);
          *(u16x4*)(Obf + ((size_t)b * TP_ + t) * 128 + ml) = pk;
          if constexpr (DUPF) {
            *(float4*)(p.dupO0 + ((size_t)b * TP_ + t) * 128 + ml) =
                make_float4(nv[0], nv[1], nv[2], nv[3]);
            *(u16x4*)(p.dupObf + ((size_t)b * TP_ + t) * 128 + ml) = pk;
          }
          if constexpr (WF) {
            if (t < T_) {
#pragma unroll
              for (int r = 0; r < 4; ++r)
                p.feat[((size_t)b * 128 + ml + r) * T_ + t] = nv[r];
            }
          }
        } else {
          float* ptr = O1 + ((size_t)b * TP_ + t) * 128 + ml;
          float4 old = *(float4*)ptr;
          float nv[4] = {old.x + rsv * v[0] + cc[0], old.y + rsv * v[1] + cc[1],
                         old.z + rsv * v[2] + cc[2], old.w + rsv * v[3] + cc[3]};
          *(float4*)ptr = make_float4(nv[0], nv[1], nv[2], nv[3]);
          if constexpr (DUPF) {
            *(float4*)(p.dupO1 + ((size_t)b * TP_ + t) * 128 + ml) =
                make_float4(nv[0], nv[1], nv[2], nv[3]);
          }
        }
      }
    }
  } else {  // EPI 3: heads scatter to [b][256][4000]
    float* O0 = br2 ? p.O0b : p.O0a;
    const float* bias = br2 ? p.bias1 : p.bias0;
#pragma unroll
    for (int i = 0; i < 4; ++i) {
      const int mg = m0 + wm * 64 + i * 16 + lg * 4;
#pragma unroll
      for (int j = 0; j < NJ; ++j) {
        const int t = t0 + wn * (TN / 2) + j * 16 + lt;
        if (t < T_) {
          f32x4 v = acc[i][j];
#pragma unroll
          for (int r = 0; r < 4; ++r)
            O0[((size_t)b * 256 + mg + r) * T_ + t] = v[r] + bias[mg + r];
        }
      }
    }
  }
}

// ---------------- depthwise dilated conv, [t][h], unconditional loads ------
// Y points at the DATA base (halo rows live at [-YHAL,0) and [TP_,TP_+YHAL)).
__global__ __launch_bounds__(256) void dw3(
    const unsigned short* __restrict__ Y, unsigned short* __restrict__ U,
    const float* __restrict__ dww0, const float* __restrict__ dww1,
    const float* __restrict__ dwb0, const float* __restrict__ dwb1,
    const float* __restrict__ g10, const float* __restrict__ g11,
    const float* __restrict__ b10, const float* __restrict__ b11,
    const float* __restrict__ p20, const float* __restrict__ p21,
    const float* __restrict__ sIn0, const float* __restrict__ sIn1, float invN,
    float* __restrict__ sOut0, float* __restrict__ sOut1, int dil, int halfY) {
  const int q = blockIdx.y;
  const bool br2 = q >= halfY;
  const int b = br2 ? q - halfY : q;
  const float* dww = br2 ? dww1 : dww0;
  const float* dwb = br2 ? dwb1 : dwb0;
  const float* g1  = br2 ? g11 : g10;
  const float* b1  = br2 ? b11 : b10;
  const float* p2p = br2 ? p21 : p20;
  const float* sIn = br2 ? sIn1 : sIn0;
  float* sOut      = br2 ? sOut1 : sOut0;
  const int tid = threadIdx.x;
  const int hc = (tid & 63) * 8;
  const int tbase = blockIdx.x * 16 + (tid >> 6) * 4;

  const float mean = sIn[b * 2] * invN;
  const float rs = rsqrtf(sIn[b * 2 + 1] * invN - mean * mean + 1e-8f);
  float sA[8], oA[8], w0[8], w1[8], w2[8], bb[8];
#pragma unroll
  for (int j = 0; j < 8; ++j) {
    sA[j] = rs * g1[hc + j];
    oA[j] = b1[hc + j] - mean * sA[j];
    w0[j] = dww[(hc + j) * 3 + 0];
    w1[j] = dww[(hc + j) * 3 + 1];
    w2[j] = dww[(hc + j) * 3 + 2];
    bb[j] = dwb[hc + j];
  }
  const float alpha = p2p[0];
  const unsigned short* Yb = Y + (size_t)q * YSST;
  unsigned short* Ub = U + (size_t)q * USST;

  // phase 1: issue ALL loads (unconditional — halo rows are allocated)
  s8v xm[4], x0[4], xp[4];
#pragma unroll
  for (int i = 0; i < 4; ++i) {
    const int t = tbase + i;
    xm[i] = *(const s8v*)(Yb + (size_t)(t - dil) * YROW + hc);
    x0[i] = *(const s8v*)(Yb + (size_t)t * YROW + hc);
    xp[i] = *(const s8v*)(Yb + (size_t)(t + dil) * YROW + hc);
  }

  float s1 = 0.f, s2 = 0.f;
#pragma unroll
  for (int i = 0; i < 4; ++i) {
    const int t = tbase + i;
    const bool vm = (t - dil >= 0), vp = (t + dil < T_);
    s8v out;
#pragma unroll
    for (int j = 0; j < 8; ++j) {
      float fm = vm ? (bf2f((unsigned short)xm[i][j]) * sA[j] + oA[j]) : 0.f;
      float f0 = bf2f((unsigned short)x0[i][j]) * sA[j] + oA[j];
      float fp = vp ? (bf2f((unsigned short)xp[i][j]) * sA[j] + oA[j]) : 0.f;
      float v = fmaf(w0[j], fm, fmaf(w1[j], f0, fmaf(w2[j], fp, bb[j])));
      v = v >= 0.f ? v : alpha * v;
      unsigned short u = f2bf(v);
      out[j] = (short)u;
      float f = bf2f(u);
      s1 += f; s2 += f * f;
    }
    *(s8v*)(Ub + (size_t)t * YROW + hc) = out;
  }
#pragma unroll
  for (int off = 32; off > 0; off >>= 1) {
    s1 += __shfl_xor(s1, off);
    s2 += __shfl_xor(s2, off);
  }
  __shared__ float red[8];
  const int lane = tid & 63, wv = tid >> 6;
  if (lane == 0) { red[wv] = s1; red[4 + wv] = s2; }
  __syncthreads();
  if (tid == 0) {
    atomicAdd(&sOut[b * 2 + 0], red[0] + red[1] + red[2] + red[3]);
    atomicAdd(&sOut[b * 2 + 1], red[4] + red[5] + red[6] + red[7]);
  }
}

// ---------------------------------------------------------------------------
extern "C" void kernel_launch(void* const* d_in, const int* in_sizes, int n_in,
                              void* d_out, int out_size, void* d_ws, size_t ws_size,
                              hipStream_t stream) {
  (void)in_sizes; (void)n_in; (void)out_size; (void)ws_size;
  const float* input = (const float*)d_in[0];
  const float* ln1_g = (const float*)d_in[1];
  const float* ln1_b = (const float*)d_in[2];
  const float* bn1_w = (const float*)d_in[3];
  const float* bn1_b = (const float*)d_in[4];
  const float* pw_w  = (const float*)d_in[5];
  const float* pw_b  = (const float*)d_in[6];
  const float* dw_w  = (const float*)d_in[7];
  const float* dw_b  = (const float*)d_in[8];
  const float* res_w = (const float*)d_in[9];
  const float* res_b = (const float*)d_in[10];
  const float* sk_w  = (const float*)d_in[11];
  const float* sk_b  = (const float*)d_in[12];
  const float* p1    = (const float*)d_in[13];
  const float* p2    = (const float*)d_in[14];
  const float* n1g   = (const float*)d_in[15];
  const float* n1b   = (const float*)d_in[16];
  const float* n2g   = (const float*)d_in[17];
  const float* n2b   = (const float*)d_in[18];
  const float* h1_p  = (const float*)d_in[19];
  const float* h1_w  = (const float*)d_in[20];
  const float* h1_b  = (const float*)d_in[21];
  const float* h2_p  = (const float*)d_in[22];
  const float* h2_w  = (const float*)d_in[23];
  const float* h2_b  = (const float*)d_in[24];

  float* out1 = (float*)d_out;
  float* out2 = out1 + 4096000;   // [4,256,4000]
  float* feat = out1 + 8192000;   // [4,128,4000]

  char* base = (char*)d_ws;
  float* OUTS  = (float*)base;                  base += (size_t)B_ * TP_ * 128 * 4;
  float* SKIP  = (float*)base;                  base += (size_t)B_ * TP_ * 128 * 4;
  float* OUT2  = (float*)base;                  base += (size_t)B_ * TP_ * 128 * 4;
  float* SKIP2 = (float*)base;                  base += (size_t)B_ * TP_ * 128 * 4;
  unsigned short* OUTbf  = (unsigned short*)base; base += (size_t)B_ * TP_ * 128 * 2;
  unsigned short* OUT2bf = (unsigned short*)base; base += (size_t)B_ * TP_ * 128 * 2;
  unsigned short* Ybuf = (unsigned short*)base; base += (size_t)8 * YSST * 2;  // 8 slots + halo
  unsigned short* Ubuf = (unsigned short*)base; base += (size_t)8 * USST * 2;  // 8 slots
  unsigned short* Xt   = (unsigned short*)base; base += (size_t)B_ * TP_ * 256 * 2;
  unsigned short* SKbf = (unsigned short*)base; base += (size_t)2 * B_ * TP_ * 128 * 2;
  unsigned short* Wpw  = (unsigned short*)base; base += (size_t)32 * 512 * 128 * 2;
  unsigned short* Wg   = (unsigned short*)base; base += (size_t)32 * 256 * 512 * 2;
  unsigned short* Wbn  = (unsigned short*)base; base += (size_t)128 * 256 * 2;
  unsigned short* Wh1  = (unsigned short*)base; base += (size_t)256 * 128 * 2;
  unsigned short* Wh2  = (unsigned short*)base; base += (size_t)256 * 128 * 2;
  float* UVu   = (float*)base;                  base += (size_t)32 * 256 * 4;
  float* UVv   = (float*)base;                  base += (size_t)32 * 256 * 4;
  float* STATS = (float*)base;

  unsigned short* YbufD = Ybuf + (size_t)YHAL * YROW;  // data base (halo before)
  const int npr = B_ * TP_ * 128;

  hipMemsetAsync(STATS, 0, 65 * 8 * sizeof(float), stream);
  hipMemsetAsync(SKIP, 0, (size_t)B_ * TP_ * 128 * sizeof(float), stream);

  const float invN_in = 1.0f / (256.0f * 4000.0f);
  const float invN_h  = 1.0f / (512.0f * 4000.0f);

  // weight prep
  cvt_bf<<<2048, 256, 0, stream>>>(pw_w, Wpw, 32 * 512 * 128);
  cvt_bf<<<128, 256, 0, stream>>>(bn1_w, Wbn, 128 * 256);
  cvt_bf<<<128, 256, 0, stream>>>(h1_w, Wh1, 256 * 128);
  cvt_bf<<<128, 256, 0, stream>>>(h2_w, Wh2, 256 * 128);
  fold_rs<<<32 * 256, 256, 0, stream>>>(res_w, sk_w, n2g, n2b, Wg, UVu, UVv);

  // input GN -> bf16 [t][256] -> bottleneck GEMM
  gn_stats<<<dim3(64, B_), 256, 0, stream>>>(input, STATS, 256 * T_);
  tin<<<dim3(63, 4, B_), 256, 0, stream>>>(input, Xt, ln1_g, ln1_b, STATS, invN_in);
  {
    MMP q{}; q.A0 = Wbn; q.B0 = Xt; q.bias0 = bn1_b; q.O0a = OUTS; q.Obf0 = OUTbf;
    q.K = 256;
    mm6<0, 128, 0><<<dim3(32, 1, B_), 256, 0, stream>>>(q);
  }

  // ---- serial blocks 0..15 (shared trunk)
  auto pw_one = [&](int i) {
    MMP q{}; q.A0 = Wpw + (size_t)i * 512 * 128; q.B0 = OUTbf;
    q.bias0 = pw_b + (size_t)i * 512; q.Obf0 = YbufD; q.al0 = p1 + i;
    q.so0 = STATS + (size_t)(1 + 2 * i) * 8; q.K = 128;
    mm6<1, 128, 0><<<dim3(32, 4, B_), 256, 0, stream>>>(q);
  };
  auto dw_one = [&](int i) {
    float* sA = STATS + (size_t)(1 + 2 * i) * 8;
    float* sB = STATS + (size_t)(2 + 2 * i) * 8;
    dw3<<<dim3(250, B_), 256, 0, stream>>>(
        YbufD, Ubuf, dw_w + (size_t)i * 512 * 3, nullptr,
        dw_b + (size_t)i * 512, nullptr, n1g + (size_t)i * 512, nullptr,
        n1b + (size_t)i * 512, nullptr, p2 + i, nullptr, sA, nullptr, invN_h,
        sB, nullptr, 1 << (i & 7), 99);
  };
  auto rs_one = [&](int i, int flg) {
    MMP q{}; q.A0 = Wg + (size_t)i * 256 * 512; q.B0 = Ubuf;
    q.O0a = OUTS; q.O1a = SKIP; q.Obf0 = OUTbf;
    q.si0 = STATS + (size_t)(2 + 2 * i) * 8; q.invN = invN_h;
    q.Uc0 = UVu + (size_t)i * 256; q.Vc0 = UVv + (size_t)i * 256;
    q.rb0 = res_b + (size_t)i * 128; q.sb0 = sk_b + (size_t)i * 128;
    q.feat = feat; q.dupO0 = OUT2; q.dupObf = OUT2bf; q.dupO1 = SKIP2;
    q.K = 512;
    if (flg == 2)      mm6<2, 64, 2><<<dim3(64, 2, B_), 256, 0, stream>>>(q);
    else if (flg == 4) mm6<2, 64, 4><<<dim3(64, 2, B_), 256, 0, stream>>>(q);
    else               mm6<2, 64, 0><<<dim3(64, 2, B_), 256, 0, stream>>>(q);
  };

  for (int i = 0; i < 16; ++i) {
    pw_one(i);
    dw_one(i);
    rs_one(i, (i == 7) ? 2 : (i == 15) ? 4 : 0);
  }

  // ---- paired blocks: branch1 = 16+j, branch2 = 24+j
  for (int j = 0; j < 8; ++j) {
    const int i1 = 16 + j, i2 = 24 + j;
    float* sA1 = STATS + (size_t)(1 + 2 * i1) * 8;
    float* sB1 = STATS + (size_t)(2 + 2 * i1) * 8;
    float* sA2 = STATS + (size_t)(1 + 2 * i2) * 8;
    float* sB2 = STATS + (size_t)(2 + 2 * i2) * 8;
    {
      MMP q{};
      q.A0 = Wpw + (size_t)i1 * 512 * 128; q.A1 = Wpw + (size_t)i2 * 512 * 128;
      q.B0 = OUTbf; q.B1 = OUT2bf;
      q.bias0 = pw_b + (size_t)i1 * 512; q.bias1 = pw_b + (size_t)i2 * 512;
      q.Obf0 = YbufD; q.Obf1 = YbufD + 4 * YSST;
      q.al0 = p1 + i1; q.al1 = p1 + i2;
      q.so0 = sA1; q.so1 = sA2; q.K = 128;
      mm6<1, 128, 1><<<dim3(32, 4, 2 * B_), 256, 0, stream>>>(q);
    }
    dw3<<<dim3(250, 2 * B_), 256, 0, stream>>>(
        YbufD, Ubuf,
        dw_w + (size_t)i1 * 512 * 3, dw_w + (size_t)i2 * 512 * 3,
        dw_b + (size_t)i1 * 512, dw_b + (size_t)i2 * 512,
        n1g + (size_t)i1 * 512, n1g + (size_t)i2 * 512,
        n1b + (size_t)i1 * 512, n1b + (size_t)i2 * 512,
        p2 + i1, p2 + i2, sA1, sA2, invN_h, sB1, sB2, 1 << (j & 7), B_);
    {
      MMP q{};
      q.A0 = Wg + (size_t)i1 * 256 * 512; q.A1 = Wg + (size_t)i2 * 256 * 512;
      q.B0 = Ubuf; q.B1 = Ubuf + 4 * USST;
      q.O0a = OUTS; q.O0b = OUT2; q.O1a = SKIP; q.O1b = SKIP2;
      q.Obf0 = OUTbf; q.Obf1 = OUT2bf;
      q.si0 = sB1; q.si1 = sB2; q.invN = invN_h;
      q.Uc0 = UVu + (size_t)i1 * 256; q.Uc1 = UVu + (size_t)i2 * 256;
      q.Vc0 = UVv + (size_t)i1 * 256; q.Vc1 = UVv + (size_t)i2 * 256;
      q.rb0 = res_b + (size_t)i1 * 128; q.rb1 = res_b + (size_t)i2 * 128;
      q.sb0 = sk_b + (size_t)i1 * 128; q.sb1 = sk_b + (size_t)i2 * 128;
      q.K = 512;
      mm6<2, 128, 1><<<dim3(32, 2, 2 * B_), 256, 0, stream>>>(q);
    }
  }

  // ---- heads (both in one pass)
  prelu2<<<2048, 256, 0, stream>>>(SKIP, SKIP2, SKbf, h1_p, h2_p, npr);
  {
    MMP q{};
    q.A0 = Wh1; q.A1 = Wh2;
    q.B0 = SKbf; q.B1 = SKbf + npr;
    q.bias0 = h1_b; q.bias1 = h2_b;
    q.O0a = out1; q.O0b = out2; q.K = 128;
    mm6<3, 128, 1><<<dim3(32, 2, 2 * B_), 256, 0, stream>>>(q);
  }
}

// Round 8
// 1268.720 us; speedup vs baseline: 4.8426x; 1.6732x over previous
//
#include <hip/hip_runtime.h>
#include <hip/hip_bf16.h>

// ---------------------------------------------------------------------------
// Conv-TasNet TCN, bf16-MFMA v7.
// vs v6: GN stats atomics SPREAD over 64 sub-slots (slot = [64][8] floats,
// producer adds to sub-slot blockIdx.x&63, consumer wave-reduces 64 partials
// in-register). Removes the ~13ns/atomic same-address L2 serialization that
// dominated dw3/pw dispatch times.
// ---------------------------------------------------------------------------

#define T_  4000
#define TP_ 4096
#define B_  4
#define YHAL 128
#define YROW 512
#define YSST ((size_t)(TP_ + 2 * YHAL) * YROW)
#define USST ((size_t)TP_ * YROW)
#define NSUB 64
#define SLOTW (NSUB * 8)

typedef __attribute__((ext_vector_type(8))) short  s8v;
typedef __attribute__((ext_vector_type(4))) float  f32x4;
typedef __attribute__((ext_vector_type(4))) unsigned short u16x4;

__device__ __forceinline__ float bf2f(unsigned short u) {
  unsigned int i = ((unsigned int)u) << 16;
  float f; __builtin_memcpy(&f, &i, 4); return f;
}
__device__ __forceinline__ unsigned short f2bf(float f) {
  unsigned int i; __builtin_memcpy(&i, &f, 4);
  unsigned int r = i + 0x7fffu + ((i >> 16) & 1u);
  return (unsigned short)(r >> 16);
}

__device__ __forceinline__ void g2lds16(const void* g, void* l) {
  __builtin_amdgcn_global_load_lds(
      (const __attribute__((address_space(1))) unsigned int*)g,
      (__attribute__((address_space(3))) unsigned int*)l, 16, 0, 0);
}

// consumer-side: sum the 64 sub-slot partials of one stats slot (per-wave).
__device__ __forceinline__ void stats_sum(const float* __restrict__ si, int b,
                                          float& u, float& q) {
  const int lane = threadIdx.x & 63;
  u = si[lane * 8 + b * 2 + 0];
  q = si[lane * 8 + b * 2 + 1];
#pragma unroll
  for (int off = 32; off > 0; off >>= 1) {
    u += __shfl_xor(u, off);
    q += __shfl_xor(q, off);
  }
}

// ---------------- per-sample sum/sumsq over contiguous [C*T] ---------------
__global__ __launch_bounds__(256) void gn_stats(const float* __restrict__ X,
                                                float* __restrict__ statsOut, int n) {
  const int b = blockIdx.y;
  const float4* xp = (const float4*)(X + (size_t)b * n);
  const int n4 = n >> 2;
  float s1 = 0.f, s2 = 0.f;
  for (int idx = blockIdx.x * 256 + threadIdx.x; idx < n4; idx += gridDim.x * 256) {
    float4 v = xp[idx];
    s1 += v.x + v.y + v.z + v.w;
    s2 += v.x * v.x + v.y * v.y + v.z * v.z + v.w * v.w;
  }
#pragma unroll
  for (int off = 32; off > 0; off >>= 1) {
    s1 += __shfl_xor(s1, off);
    s2 += __shfl_xor(s2, off);
  }
  __shared__ float red[8];
  const int lane = threadIdx.x & 63, wv = threadIdx.x >> 6;
  if (lane == 0) { red[wv] = s1; red[4 + wv] = s2; }
  __syncthreads();
  if (threadIdx.x == 0) {
    float* dst = statsOut + (size_t)(blockIdx.x & (NSUB - 1)) * 8 + b * 2;
    atomicAdd(&dst[0], red[0] + red[1] + red[2] + red[3]);
    atomicAdd(&dst[1], red[4] + red[5] + red[6] + red[7]);
  }
}

// ---------------- weight prep ----------------------------------------------
__global__ __launch_bounds__(256) void cvt_bf(const float* __restrict__ s,
                                              unsigned short* __restrict__ d, int n) {
  for (int i = blockIdx.x * 256 + threadIdx.x; i < n; i += gridDim.x * 256)
    d[i] = f2bf(s[i]);
}

__global__ __launch_bounds__(256) void fold_rs(
    const float* __restrict__ rw, const float* __restrict__ sw,
    const float* __restrict__ g2a, const float* __restrict__ b2a,
    unsigned short* __restrict__ Wg, float* __restrict__ Ucb,
    float* __restrict__ Vcb) {
  const int row = blockIdx.x;                 // i*256 + m
  const int i = row >> 8, m = row & 255;
  const float* src = (m < 128) ? rw + ((size_t)i * 128 + m) * 512
                               : sw + ((size_t)i * 128 + (m - 128)) * 512;
  const float* g = g2a + (size_t)i * 512;
  const float* bb = b2a + (size_t)i * 512;
  unsigned short* dst = Wg + (size_t)row * 512;
  float u = 0.f, v = 0.f;
  for (int h = threadIdx.x; h < 512; h += 256) {
    float wgt = src[h] * g[h];
    dst[h] = f2bf(wgt);
    u += wgt; v += src[h] * bb[h];
  }
#pragma unroll
  for (int off = 32; off > 0; off >>= 1) {
    u += __shfl_xor(u, off);
    v += __shfl_xor(v, off);
  }
  __shared__ float red[8];
  const int lane = threadIdx.x & 63, wv = threadIdx.x >> 6;
  if (lane == 0) { red[wv] = u; red[4 + wv] = v; }
  __syncthreads();
  if (threadIdx.x == 0) {
    Ucb[row] = red[0] + red[1] + red[2] + red[3];
    Vcb[row] = red[4] + red[5] + red[6] + red[7];
  }
}

// both heads' prelu+cvt in one launch
__global__ __launch_bounds__(256) void prelu2(const float* __restrict__ S0,
                                              const float* __restrict__ S1,
                                              unsigned short* __restrict__ D,
                                              const float* __restrict__ a0p,
                                              const float* __restrict__ a1p, int n) {
  const float a0 = a0p[0], a1 = a1p[0];
  for (int i = blockIdx.x * 256 + threadIdx.x; i < 2 * n; i += gridDim.x * 256) {
    float v = (i < n) ? S0[i] : S1[i - n];
    float a = (i < n) ? a0 : a1;
    v = v >= 0.f ? v : a * v;
    D[i] = f2bf(v);
  }
}

// ---------------- input transpose + GN affine + bf16 -----------------------
__global__ __launch_bounds__(256) void tin(const float* __restrict__ X,
                                           unsigned short* __restrict__ Xt,
                                           const float* __restrict__ g,
                                           const float* __restrict__ bt,
                                           const float* __restrict__ sIn, float invN) {
  const int b = blockIdx.z, c0 = blockIdx.y * 64, t0 = blockIdx.x * 64;
  __shared__ float tile[64][65];
  const int tid = threadIdx.x;
  float su, sq;
  stats_sum(sIn, b, su, sq);
  const float mean = su * invN;
  const float rs = rsqrtf(sq * invN - mean * mean + 1e-8f);
  {
    const int cl = tid >> 2, tq = (tid & 3) * 16;
    const float* Xr = X + ((size_t)b * 256 + c0 + cl) * T_;
#pragma unroll
    for (int j = 0; j < 4; ++j) {
      int tt = t0 + tq + j * 4;
      float4 v;
      if (tt + 3 < T_) v = *(const float4*)(Xr + tt);
      else {
        v.x = (tt + 0 < T_) ? Xr[tt + 0] : 0.f;
        v.y = (tt + 1 < T_) ? Xr[tt + 1] : 0.f;
        v.z = (tt + 2 < T_) ? Xr[tt + 2] : 0.f;
        v.w = (tt + 3 < T_) ? Xr[tt + 3] : 0.f;
      }
      tile[cl][tq + j * 4 + 0] = v.x; tile[cl][tq + j * 4 + 1] = v.y;
      tile[cl][tq + j * 4 + 2] = v.z; tile[cl][tq + j * 4 + 3] = v.w;
    }
  }
  __syncthreads();
  {
    const int tl = tid >> 2, cq = (tid & 3) * 16;
    const int t = t0 + tl;
    if (t < T_) {
      unsigned short* dst = Xt + ((size_t)b * TP_ + t) * 256 + c0 + cq;
      s8v u0, u1;
#pragma unroll
      for (int j = 0; j < 16; ++j) {
        int c = c0 + cq + j;
        float sc = rs * g[c];
        float oc = bt[c] - mean * sc;
        unsigned short uu = f2bf(tile[cq + j][tl] * sc + oc);
        if (j < 8) u0[j] = (short)uu; else u1[j - 8] = (short)uu;
      }
      *(s8v*)dst = u0;
      *(s8v*)(dst + 8) = u1;
    }
  }
}

// ---------------- mm6 params ------------------------------------------------
struct MMP {
  const unsigned short *A0, *A1, *B0, *B1;
  const float *bias0, *bias1;
  float *O0a, *O0b, *O1a, *O1b;
  unsigned short *Obf0, *Obf1;
  const float *al0, *al1;
  float *so0, *so1;
  const float *si0, *si1;
  const float *Uc0, *Uc1, *Vc0, *Vc1, *rb0, *rb1, *sb0, *sb1;
  float* feat;
  float* dupO0; unsigned short* dupObf; float* dupO1;
  int K; float invN;
};

// ---------------- clean bf16 MFMA GEMM, 128m x TNt x 64k -------------------
// EPI 0: O0 fp32 [t][128] = v+bias, Obf shadow                (bn1)
// EPI 1: prelu -> Obf bf16 Y-slot (halo stride YSST) + GN stats (pw)
// EPI 2: GN2-folded; y==0: res RMW O0 + shadow; y==1: skip RMW O1
//        WF: also write feat [128][4000]; DUP: also write fork copies
// EPI 3: masked fp32 scatter O0[b][256][4000] = v+bias         (heads)
// FLG: 1=PAIR (blockIdx.z >= gridDim.z/2 -> branch-2 pointers)
template <int EPI, int TN, int FLG>
__global__ __launch_bounds__(256) void mm6(MMP p) {
  constexpr bool PAIR = (FLG & 1) != 0;
  constexpr bool WF   = (FLG & 2) != 0;
  constexpr bool DUPF = (FLG & 4) != 0;
  constexpr int NJ = TN / 32;
  __shared__ unsigned short As[128 * 64];
  __shared__ unsigned short Bs[TN * 64];
  __shared__ float redw[8];
  int b = blockIdx.z; bool br2 = false;
  if constexpr (PAIR) {
    const int h = gridDim.z >> 1;
    if (b >= h) { br2 = true; b -= h; }
  }
  const int K = p.K;
  const unsigned short* A  = br2 ? p.A1 : p.A0;
  const unsigned short* Bm = br2 ? p.B1 : p.B0;
  const int m0 = blockIdx.y * 128;
  const int t0 = blockIdx.x * TN;
  const int tid = threadIdx.x;
  const int lane = tid & 63;
  const int w = tid >> 6;
  const int wm = w >> 1, wn = w & 1;
  const int lt = lane & 15, lg = lane >> 4;
  const unsigned short* Ab = A + (size_t)m0 * K;
  const unsigned short* Bb = Bm + ((size_t)b * TP_ + t0) * K;
  const int srow8 = lane >> 3;
  const int skc   = ((lane & 7) ^ (lane >> 3)) * 8;

  f32x4 acc[4][NJ];
#pragma unroll
  for (int i = 0; i < 4; ++i)
#pragma unroll
    for (int j = 0; j < NJ; ++j) acc[i][j] = (f32x4){0.f, 0.f, 0.f, 0.f};

  for (int k0 = 0; k0 < K; k0 += 64) {
#pragma unroll
    for (int c = 0; c < 4; ++c) {
      const int ch = w * 4 + c;
      g2lds16(Ab + (size_t)(ch * 8 + srow8) * K + k0 + skc, &As[ch * 512]);
    }
#pragma unroll
    for (int c = 0; c < NJ; ++c) {
      const int ch = w * NJ + c;
      g2lds16(Bb + (size_t)(ch * 8 + srow8) * K + k0 + skc, &Bs[ch * 512]);
    }
    __syncthreads();
#pragma unroll
    for (int ks = 0; ks < 2; ++ks) {
      s8v bfr[NJ];
#pragma unroll
      for (int j = 0; j < NJ; ++j) {
        const int R = wn * (TN / 2) + j * 16 + lt;
        bfr[j] = *(const s8v*)&Bs[R * 64 + (((ks * 4 + lg) ^ (R & 7)) * 8)];
      }
#pragma unroll
      for (int i = 0; i < 4; ++i) {
        const int R = wm * 64 + i * 16 + lt;
        s8v af = *(const s8v*)&As[R * 64 + (((ks * 4 + lg) ^ (R & 7)) * 8)];
#pragma unroll
        for (int j = 0; j < NJ; ++j)
          acc[i][j] = __builtin_amdgcn_mfma_f32_16x16x32_bf16(af, bfr[j], acc[i][j], 0, 0, 0);
      }
    }
    __syncthreads();
  }

  // ---- epilogues. D row m = m0 + wm*64 + i*16 + lg*4 + r,
  //                 D col t = t0 + wn*(TN/2) + j*16 + lt
  if constexpr (EPI == 0) {
    const float* bias = p.bias0;
#pragma unroll
    for (int i = 0; i < 4; ++i) {
      const int mg = m0 + wm * 64 + i * 16 + lg * 4;
      float4 bi = *(const float4*)(bias + mg);
#pragma unroll
      for (int j = 0; j < NJ; ++j) {
        const int t = t0 + wn * (TN / 2) + j * 16 + lt;
        f32x4 v = acc[i][j];
        float nv[4] = {v[0] + bi.x, v[1] + bi.y, v[2] + bi.z, v[3] + bi.w};
        *(float4*)(p.O0a + ((size_t)b * TP_ + t) * 128 + mg) =
            make_float4(nv[0], nv[1], nv[2], nv[3]);
        u16x4 pk;
#pragma unroll
        for (int r = 0; r < 4; ++r) pk[r] = f2bf(nv[r]);
        *(u16x4*)(p.Obf0 + ((size_t)b * TP_ + t) * 128 + mg) = pk;
      }
    }
  } else if constexpr (EPI == 1) {
    // Y-slot output with halo stride
    const float* bias = br2 ? p.bias1 : p.bias0;
    unsigned short* Obf = (br2 ? p.Obf1 : p.Obf0) + (size_t)b * YSST;
    const float aO = (br2 ? p.al1 : p.al0)[0];
    float* so = br2 ? p.so1 : p.so0;
    float s1 = 0.f, s2 = 0.f;
#pragma unroll
    for (int i = 0; i < 4; ++i) {
      const int mg = m0 + wm * 64 + i * 16 + lg * 4;
      float4 bi = *(const float4*)(bias + mg);
      float bv[4] = {bi.x, bi.y, bi.z, bi.w};
#pragma unroll
      for (int j = 0; j < NJ; ++j) {
        const int t = t0 + wn * (TN / 2) + j * 16 + lt;
        f32x4 v = acc[i][j];
        u16x4 pk;
#pragma unroll
        for (int r = 0; r < 4; ++r) {
          float f = v[r] + bv[r];
          f = f >= 0.f ? f : aO * f;
          pk[r] = f2bf(f);
        }
        *(u16x4*)(Obf + (size_t)t * YROW + mg) = pk;
        if (t < T_) {
#pragma unroll
          for (int r = 0; r < 4; ++r) { float f = bf2f(pk[r]); s1 += f; s2 += f * f; }
        }
      }
    }
#pragma unroll
    for (int off = 32; off > 0; off >>= 1) {
      s1 += __shfl_xor(s1, off);
      s2 += __shfl_xor(s2, off);
    }
    if (lane == 0) { redw[w] = s1; redw[4 + w] = s2; }
    __syncthreads();
    if (tid == 0) {
      float* dst = so + (size_t)(blockIdx.x & (NSUB - 1)) * 8 + b * 2;
      atomicAdd(&dst[0], redw[0] + redw[1] + redw[2] + redw[3]);
      atomicAdd(&dst[1], redw[4] + redw[5] + redw[6] + redw[7]);
    }
  } else if constexpr (EPI == 2) {
    float* O0 = br2 ? p.O0b : p.O0a;
    float* O1 = br2 ? p.O1b : p.O1a;
    unsigned short* Obf = br2 ? p.Obf1 : p.Obf0;
    const float* si = br2 ? p.si1 : p.si0;
    const float* Uc = br2 ? p.Uc1 : p.Uc0;
    const float* Vc = br2 ? p.Vc1 : p.Vc0;
    const float* rb = br2 ? p.rb1 : p.rb0;
    const float* sb = br2 ? p.sb1 : p.sb0;
    float su, sq;
    stats_sum(si, b, su, sq);
    const float mean = su * p.invN;
    const float rsv = rsqrtf(sq * p.invN - mean * mean + 1e-8f);
    const bool isRes = (m0 == 0);
#pragma unroll
    for (int i = 0; i < 4; ++i) {
      const int ml = wm * 64 + i * 16 + lg * 4;   // 0..127 local
      float cc[4];
#pragma unroll
      for (int r = 0; r < 4; ++r) {
        const int mgG = m0 + ml + r;
        cc[r] = Vc[mgG] - mean * rsv * Uc[mgG] + (isRes ? rb[ml + r] : sb[ml + r]);
      }
#pragma unroll
      for (int j = 0; j < NJ; ++j) {
        const int t = t0 + wn * (TN / 2) + j * 16 + lt;
        f32x4 v = acc[i][j];
        if (isRes) {
          float* ptr = O0 + ((size_t)b * TP_ + t) * 128 + ml;
          float4 old = *(float4*)ptr;
          float nv[4] = {old.x + rsv * v[0] + cc[0], old.y + rsv * v[1] + cc[1],
                         old.z + rsv * v[2] + cc[2], old.w + rsv * v[3] + cc[3]};
          *(float4*)ptr = make_float4(nv[0], nv[1], nv[2], nv[3]);
          u16x4 pk;
#pragma unroll
          for (int r = 0; r < 4; ++r) pk[r] = f2bf(nv[r]);
          *(u16x4*)(Obf + ((size_t)b * TP_ + t) * 128 + ml) = pk;
          if constexpr (DUPF) {
            *(float4*)(p.dupO0 + ((size_t)b * TP_ + t) * 128 + ml) =
                make_float4(nv[0], nv[1], nv[2], nv[3]);
            *(u16x4*)(p.dupObf + ((size_t)b * TP_ + t) * 128 + ml) = pk;
          }
          if constexpr (WF) {
            if (t < T_) {
#pragma unroll
              for (int r = 0; r < 4; ++r)
                p.feat[((size_t)b * 128 + ml + r) * T_ + t] = nv[r];
            }
          }
        } else {
          float* ptr = O1 + ((size_t)b * TP_ + t) * 128 + ml;
          float4 old = *(float4*)ptr;
          float nv[4] = {old.x + rsv * v[0] + cc[0], old.y + rsv * v[1] + cc[1],
                         old.z + rsv * v[2] + cc[2], old.w + rsv * v[3] + cc[3]};
          *(float4*)ptr = make_float4(nv[0], nv[1], nv[2], nv[3]);
          if constexpr (DUPF) {
            *(float4*)(p.dupO1 + ((size_t)b * TP_ + t) * 128 + ml) =
                make_float4(nv[0], nv[1], nv[2], nv[3]);
          }
        }
      }
    }
  } else {  // EPI 3: heads scatter to [b][256][4000]
    float* O0 = br2 ? p.O0b : p.O0a;
    const float* bias = br2 ? p.bias1 : p.bias0;
#pragma unroll
    for (int i = 0; i < 4; ++i) {
      const int mg = m0 + wm * 64 + i * 16 + lg * 4;
#pragma unroll
      for (int j = 0; j < NJ; ++j) {
        const int t = t0 + wn * (TN / 2) + j * 16 + lt;
        if (t < T_) {
          f32x4 v = acc[i][j];
#pragma unroll
          for (int r = 0; r < 4; ++r)
            O0[((size_t)b * 256 + mg + r) * T_ + t] = v[r] + bias[mg + r];
        }
      }
    }
  }
}

// ---------------- depthwise dilated conv, [t][h], unconditional loads ------
// Y points at the DATA base (halo rows live at [-YHAL,0) and [TP_,TP_+YHAL)).
__global__ __launch_bounds__(256) void dw3(
    const unsigned short* __restrict__ Y, unsigned short* __restrict__ U,
    const float* __restrict__ dww0, const float* __restrict__ dww1,
    const float* __restrict__ dwb0, const float* __restrict__ dwb1,
    const float* __restrict__ g10, const float* __restrict__ g11,
    const float* __restrict__ b10, const float* __restrict__ b11,
    const float* __restrict__ p20, const float* __restrict__ p21,
    const float* __restrict__ sIn0, const float* __restrict__ sIn1, float invN,
    float* __restrict__ sOut0, float* __restrict__ sOut1, int dil, int halfY) {
  const int q = blockIdx.y;
  const bool br2 = q >= halfY;
  const int b = br2 ? q - halfY : q;
  const float* dww = br2 ? dww1 : dww0;
  const float* dwb = br2 ? dwb1 : dwb0;
  const float* g1  = br2 ? g11 : g10;
  const float* b1  = br2 ? b11 : b10;
  const float* p2p = br2 ? p21 : p20;
  const float* sIn = br2 ? sIn1 : sIn0;
  float* sOut      = br2 ? sOut1 : sOut0;
  const int tid = threadIdx.x;
  const int hc = (tid & 63) * 8;
  const int tbase = blockIdx.x * 16 + (tid >> 6) * 4;

  float su, sq2;
  stats_sum(sIn, b, su, sq2);
  const float mean = su * invN;
  const float rs = rsqrtf(sq2 * invN - mean * mean + 1e-8f);
  float sA[8], oA[8], w0[8], w1[8], w2[8], bb[8];
#pragma unroll
  for (int j = 0; j < 8; ++j) {
    sA[j] = rs * g1[hc + j];
    oA[j] = b1[hc + j] - mean * sA[j];
    w0[j] = dww[(hc + j) * 3 + 0];
    w1[j] = dww[(hc + j) * 3 + 1];
    w2[j] = dww[(hc + j) * 3 + 2];
    bb[j] = dwb[hc + j];
  }
  const float alpha = p2p[0];
  const unsigned short* Yb = Y + (size_t)q * YSST;
  unsigned short* Ub = U + (size_t)q * USST;

  // phase 1: issue ALL loads (unconditional — halo rows are allocated)
  s8v xm[4], x0[4], xp[4];
#pragma unroll
  for (int i = 0; i < 4; ++i) {
    const int t = tbase + i;
    xm[i] = *(const s8v*)(Yb + (size_t)(t - dil) * YROW + hc);
    x0[i] = *(const s8v*)(Yb + (size_t)t * YROW + hc);
    xp[i] = *(const s8v*)(Yb + (size_t)(t + dil) * YROW + hc);
  }

  float s1 = 0.f, s2 = 0.f;
#pragma unroll
  for (int i = 0; i < 4; ++i) {
    const int t = tbase + i;
    const bool vm = (t - dil >= 0), vp = (t + dil < T_);
    s8v out;
#pragma unroll
    for (int j = 0; j < 8; ++j) {
      float fm = vm ? (bf2f((unsigned short)xm[i][j]) * sA[j] + oA[j]) : 0.f;
      float f0 = bf2f((unsigned short)x0[i][j]) * sA[j] + oA[j];
      float fp = vp ? (bf2f((unsigned short)xp[i][j]) * sA[j] + oA[j]) : 0.f;
      float v = fmaf(w0[j], fm, fmaf(w1[j], f0, fmaf(w2[j], fp, bb[j])));
      v = v >= 0.f ? v : alpha * v;
      unsigned short u = f2bf(v);
      out[j] = (short)u;
      float f = bf2f(u);
      s1 += f; s2 += f * f;
    }
    *(s8v*)(Ub + (size_t)t * YROW + hc) = out;
  }
#pragma unroll
  for (int off = 32; off > 0; off >>= 1) {
    s1 += __shfl_xor(s1, off);
    s2 += __shfl_xor(s2, off);
  }
  __shared__ float red[8];
  const int lane = tid & 63, wv = tid >> 6;
  if (lane == 0) { red[wv] = s1; red[4 + wv] = s2; }
  __syncthreads();
  if (tid == 0) {
    float* dst = sOut + (size_t)(blockIdx.x & (NSUB - 1)) * 8 + b * 2;
    atomicAdd(&dst[0], red[0] + red[1] + red[2] + red[3]);
    atomicAdd(&dst[1], red[4] + red[5] + red[6] + red[7]);
  }
}

// ---------------------------------------------------------------------------
extern "C" void kernel_launch(void* const* d_in, const int* in_sizes, int n_in,
                              void* d_out, int out_size, void* d_ws, size_t ws_size,
                              hipStream_t stream) {
  (void)in_sizes; (void)n_in; (void)out_size; (void)ws_size;
  const float* input = (const float*)d_in[0];
  const float* ln1_g = (const float*)d_in[1];
  const float* ln1_b = (const float*)d_in[2];
  const float* bn1_w = (const float*)d_in[3];
  const float* bn1_b = (const float*)d_in[4];
  const float* pw_w  = (const float*)d_in[5];
  const float* pw_b  = (const float*)d_in[6];
  const float* dw_w  = (const float*)d_in[7];
  const float* dw_b  = (const float*)d_in[8];
  const float* res_w = (const float*)d_in[9];
  const float* res_b = (const float*)d_in[10];
  const float* sk_w  = (const float*)d_in[11];
  const float* sk_b  = (const float*)d_in[12];
  const float* p1    = (const float*)d_in[13];
  const float* p2    = (const float*)d_in[14];
  const float* n1g   = (const float*)d_in[15];
  const float* n1b   = (const float*)d_in[16];
  const float* n2g   = (const float*)d_in[17];
  const float* n2b   = (const float*)d_in[18];
  const float* h1_p  = (const float*)d_in[19];
  const float* h1_w  = (const float*)d_in[20];
  const float* h1_b  = (const float*)d_in[21];
  const float* h2_p  = (const float*)d_in[22];
  const float* h2_w  = (const float*)d_in[23];
  const float* h2_b  = (const float*)d_in[24];

  float* out1 = (float*)d_out;
  float* out2 = out1 + 4096000;   // [4,256,4000]
  float* feat = out1 + 8192000;   // [4,128,4000]

  char* base = (char*)d_ws;
  float* OUTS  = (float*)base;                  base += (size_t)B_ * TP_ * 128 * 4;
  float* SKIP  = (float*)base;                  base += (size_t)B_ * TP_ * 128 * 4;
  float* OUT2  = (float*)base;                  base += (size_t)B_ * TP_ * 128 * 4;
  float* SKIP2 = (float*)base;                  base += (size_t)B_ * TP_ * 128 * 4;
  unsigned short* OUTbf  = (unsigned short*)base; base += (size_t)B_ * TP_ * 128 * 2;
  unsigned short* OUT2bf = (unsigned short*)base; base += (size_t)B_ * TP_ * 128 * 2;
  unsigned short* Ybuf = (unsigned short*)base; base += (size_t)8 * YSST * 2;  // 8 slots + halo
  unsigned short* Ubuf = (unsigned short*)base; base += (size_t)8 * USST * 2;  // 8 slots
  unsigned short* Xt   = (unsigned short*)base; base += (size_t)B_ * TP_ * 256 * 2;
  unsigned short* SKbf = (unsigned short*)base; base += (size_t)2 * B_ * TP_ * 128 * 2;
  unsigned short* Wpw  = (unsigned short*)base; base += (size_t)32 * 512 * 128 * 2;
  unsigned short* Wg   = (unsigned short*)base; base += (size_t)32 * 256 * 512 * 2;
  unsigned short* Wbn  = (unsigned short*)base; base += (size_t)128 * 256 * 2;
  unsigned short* Wh1  = (unsigned short*)base; base += (size_t)256 * 128 * 2;
  unsigned short* Wh2  = (unsigned short*)base; base += (size_t)256 * 128 * 2;
  float* UVu   = (float*)base;                  base += (size_t)32 * 256 * 4;
  float* UVv   = (float*)base;                  base += (size_t)32 * 256 * 4;
  float* STATS = (float*)base;

  unsigned short* YbufD = Ybuf + (size_t)YHAL * YROW;  // data base (halo before)
  const int npr = B_ * TP_ * 128;

  hipMemsetAsync(STATS, 0, (size_t)65 * SLOTW * sizeof(float), stream);
  hipMemsetAsync(SKIP, 0, (size_t)B_ * TP_ * 128 * sizeof(float), stream);

  const float invN_in = 1.0f / (256.0f * 4000.0f);
  const float invN_h  = 1.0f / (512.0f * 4000.0f);

  // weight prep
  cvt_bf<<<2048, 256, 0, stream>>>(pw_w, Wpw, 32 * 512 * 128);
  cvt_bf<<<128, 256, 0, stream>>>(bn1_w, Wbn, 128 * 256);
  cvt_bf<<<128, 256, 0, stream>>>(h1_w, Wh1, 256 * 128);
  cvt_bf<<<128, 256, 0, stream>>>(h2_w, Wh2, 256 * 128);
  fold_rs<<<32 * 256, 256, 0, stream>>>(res_w, sk_w, n2g, n2b, Wg, UVu, UVv);

  // input GN -> bf16 [t][256] -> bottleneck GEMM
  gn_stats<<<dim3(64, B_), 256, 0, stream>>>(input, STATS, 256 * T_);
  tin<<<dim3(63, 4, B_), 256, 0, stream>>>(input, Xt, ln1_g, ln1_b, STATS, invN_in);
  {
    MMP q{}; q.A0 = Wbn; q.B0 = Xt; q.bias0 = bn1_b; q.O0a = OUTS; q.Obf0 = OUTbf;
    q.K = 256;
    mm6<0, 128, 0><<<dim3(32, 1, B_), 256, 0, stream>>>(q);
  }

  // ---- serial blocks 0..15 (shared trunk)
  auto pw_one = [&](int i) {
    MMP q{}; q.A0 = Wpw + (size_t)i * 512 * 128; q.B0 = OUTbf;
    q.bias0 = pw_b + (size_t)i * 512; q.Obf0 = YbufD; q.al0 = p1 + i;
    q.so0 = STATS + (size_t)(1 + 2 * i) * SLOTW; q.K = 128;
    mm6<1, 128, 0><<<dim3(32, 4, B_), 256, 0, stream>>>(q);
  };
  auto dw_one = [&](int i) {
    float* sA = STATS + (size_t)(1 + 2 * i) * SLOTW;
    float* sB = STATS + (size_t)(2 + 2 * i) * SLOTW;
    dw3<<<dim3(250, B_), 256, 0, stream>>>(
        YbufD, Ubuf, dw_w + (size_t)i * 512 * 3, nullptr,
        dw_b + (size_t)i * 512, nullptr, n1g + (size_t)i * 512, nullptr,
        n1b + (size_t)i * 512, nullptr, p2 + i, nullptr, sA, nullptr, invN_h,
        sB, nullptr, 1 << (i & 7), 99);
  };
  auto rs_one = [&](int i, int flg) {
    MMP q{}; q.A0 = Wg + (size_t)i * 256 * 512; q.B0 = Ubuf;
    q.O0a = OUTS; q.O1a = SKIP; q.Obf0 = OUTbf;
    q.si0 = STATS + (size_t)(2 + 2 * i) * SLOTW; q.invN = invN_h;
    q.Uc0 = UVu + (size_t)i * 256; q.Vc0 = UVv + (size_t)i * 256;
    q.rb0 = res_b + (size_t)i * 128; q.sb0 = sk_b + (size_t)i * 128;
    q.feat = feat; q.dupO0 = OUT2; q.dupObf = OUT2bf; q.dupO1 = SKIP2;
    q.K = 512;
    if (flg == 2)      mm6<2, 64, 2><<<dim3(64, 2, B_), 256, 0, stream>>>(q);
    else if (flg == 4) mm6<2, 64, 4><<<dim3(64, 2, B_), 256, 0, stream>>>(q);
    else               mm6<2, 64, 0><<<dim3(64, 2, B_), 256, 0, stream>>>(q);
  };

  for (int i = 0; i < 16; ++i) {
    pw_one(i);
    dw_one(i);
    rs_one(i, (i == 7) ? 2 : (i == 15) ? 4 : 0);
  }

  // ---- paired blocks: branch1 = 16+j, branch2 = 24+j
  for (int j = 0; j < 8; ++j) {
    const int i1 = 16 + j, i2 = 24 + j;
    float* sA1 = STATS + (size_t)(1 + 2 * i1) * SLOTW;
    float* sB1 = STATS + (size_t)(2 + 2 * i1) * SLOTW;
    float* sA2 = STATS + (size_t)(1 + 2 * i2) * SLOTW;
    float* sB2 = STATS + (size_t)(2 + 2 * i2) * SLOTW;
    {
      MMP q{};
      q.A0 = Wpw + (size_t)i1 * 512 * 128; q.A1 = Wpw + (size_t)i2 * 512 * 128;
      q.B0 = OUTbf; q.B1 = OUT2bf;
      q.bias0 = pw_b + (size_t)i1 * 512; q.bias1 = pw_b + (size_t)i2 * 512;
      q.Obf0 = YbufD; q.Obf1 = YbufD + 4 * YSST;
      q.al0 = p1 + i1; q.al1 = p1 + i2;
      q.so0 = sA1; q.so1 = sA2; q.K = 128;
      mm6<1, 128, 1><<<dim3(32, 4, 2 * B_), 256, 0, stream>>>(q);
    }
    dw3<<<dim3(250, 2 * B_), 256, 0, stream>>>(
        YbufD, Ubuf,
        dw_w + (size_t)i1 * 512 * 3, dw_w + (size_t)i2 * 512 * 3,
        dw_b + (size_t)i1 * 512, dw_b + (size_t)i2 * 512,
        n1g + (size_t)i1 * 512, n1g + (size_t)i2 * 512,
        n1b + (size_t)i1 * 512, n1b + (size_t)i2 * 512,
        p2 + i1, p2 + i2, sA1, sA2, invN_h, sB1, sB2, 1 << (j & 7), B_);
    {
      MMP q{};
      q.A0 = Wg + (size_t)i1 * 256 * 512; q.A1 = Wg + (size_t)i2 * 256 * 512;
      q.B0 = Ubuf; q.B1 = Ubuf + 4 * USST;
      q.O0a = OUTS; q.O0b = OUT2; q.O1a = SKIP; q.O1b = SKIP2;
      q.Obf0 = OUTbf; q.Obf1 = OUT2bf;
      q.si0 = sB1; q.si1 = sB2; q.invN = invN_h;
      q.Uc0 = UVu + (size_t)i1 * 256; q.Uc1 = UVu + (size_t)i2 * 256;
      q.Vc0 = UVv + (size_t)i1 * 256; q.Vc1 = UVv + (size_t)i2 * 256;
      q.rb0 = res_b + (size_t)i1 * 128; q.rb1 = res_b + (size_t)i2 * 128;
      q.sb0 = sk_b + (size_t)i1 * 128; q.sb1 = sk_b + (size_t)i2 * 128;
      q.K = 512;
      mm6<2, 128, 1><<<dim3(32, 2, 2 * B_), 256, 0, stream>>>(q);
    }
  }

  // ---- heads (both in one pass)
  prelu2<<<2048, 256, 0, stream>>>(SKIP, SKIP2, SKbf, h1_p, h2_p, npr);
  {
    MMP q{};
    q.A0 = Wh1; q.A1 = Wh2;
    q.B0 = SKbf; q.B1 = SKbf + npr;
    q.bias0 = h1_b; q.bias1 = h2_b;
    q.O0a = out1; q.O0b = out2; q.K = 128;
    mm6<3, 128, 1><<<dim3(32, 2, 2 * B_), 256, 0, stream>>>(q);
  }
}